// Round 1
// baseline (842.102 us; speedup 1.0000x reference)
//
#include <hip/hip_runtime.h>
#include <math.h>

typedef unsigned short u16;
typedef __attribute__((ext_vector_type(8))) short short8;
typedef __attribute__((ext_vector_type(4))) float f32x4;

#define T_TOK 2048
#define H_DIM 2048
#define E_NUM 16
#define F_DIM 1024
#define EFD   16384
#define M_DIM 512

__device__ __forceinline__ u16 f2bf(float x) {
  union { float f; unsigned u; } c; c.f = x;
  unsigned r = c.u + 0x7FFFu + ((c.u >> 16) & 1u);   // RNE
  return (u16)(r >> 16);
}
__device__ __forceinline__ float bf2f(u16 h) {
  union { unsigned u; float f; } c; c.u = ((unsigned)h) << 16;
  return c.f;
}
__device__ __forceinline__ void gl_lds16(const void* g, void* l) {
  __builtin_amdgcn_global_load_lds((const __attribute__((address_space(1))) void*)g,
                                   (__attribute__((address_space(3))) void*)l, 16, 0, 0);
}

// ---------------- conversion kernels ----------------
__global__ void k_cvt(const float* __restrict__ s, u16* __restrict__ d, int n8) {
  int i = blockIdx.x * 256 + threadIdx.x;
  if (i >= n8) return;
  const float4* sp = (const float4*)(s + (size_t)i * 8);
  float4 a = sp[0], b = sp[1];
  union { short8 v; u16 e[8]; } o;
  o.e[0] = f2bf(a.x); o.e[1] = f2bf(a.y); o.e[2] = f2bf(a.z); o.e[3] = f2bf(a.w);
  o.e[4] = f2bf(b.x); o.e[5] = f2bf(b.y); o.e[6] = f2bf(b.z); o.e[7] = f2bf(b.w);
  *(short8*)(d + (size_t)i * 8) = o.v;
}

// Wd[e,h,f] -> Wdp[h, e*F+f] (bf16)
__global__ void k_cvt_wd(const float* __restrict__ wd, u16* __restrict__ wdp) {
  int i = blockIdx.x * 256 + threadIdx.x;          // over E*H*F/8
  if (i >= (E_NUM * H_DIM * F_DIM) / 8) return;
  int f8 = i & 127;                                 // F/8 = 128
  int h  = (i >> 7) & (H_DIM - 1);
  int e  = i >> 18;
  const float4* sp = (const float4*)(wd + (size_t)(e * H_DIM + h) * F_DIM + f8 * 8);
  float4 a = sp[0], b = sp[1];
  union { short8 v; u16 ee[8]; } o;
  o.ee[0] = f2bf(a.x); o.ee[1] = f2bf(a.y); o.ee[2] = f2bf(a.z); o.ee[3] = f2bf(a.w);
  o.ee[4] = f2bf(b.x); o.ee[5] = f2bf(b.y); o.ee[6] = f2bf(b.z); o.ee[7] = f2bf(b.w);
  *(short8*)(wdp + (size_t)h * EFD + e * F_DIM + f8 * 8) = o.v;
}

// ---------------- plain B^T GEMM: C[M,N] = A[M,K] * B[N,K]^T ----------------
// BM=128, BN=64, BK=32. 4 waves stacked along M (32 rows each).
// EPI==0: fp32 C.  EPI==1: bf16 C = silu(acc + bias[n]).
template<int EPI>
__global__ __launch_bounds__(256, 2)
void k_gemm(const u16* __restrict__ A, const u16* __restrict__ B, int Ndim, int Kdim,
            float* __restrict__ Cf, u16* __restrict__ Cb, const float* __restrict__ bias)
{
  __shared__ __align__(16) u16 As[128 * 32];
  __shared__ __align__(16) u16 Bs[64 * 32];
  const int tid = threadIdx.x;
  const int bm0 = blockIdx.y * 128;
  const int bn0 = blockIdx.x * 64;
  const int wid = tid >> 6, lane = tid & 63;
  const int lr = lane & 15, lk = lane >> 4;
  const int srow = tid >> 2, scol = (tid & 3) * 8;

  f32x4 zero4 = {0.f, 0.f, 0.f, 0.f};
  f32x4 acc[2][4];
#pragma unroll
  for (int m = 0; m < 2; ++m)
#pragma unroll
    for (int n = 0; n < 4; ++n) acc[m][n] = zero4;

  const u16* Ag = A + (size_t)(bm0 + srow) * Kdim + scol;
  const u16* Bg = B + (size_t)(bn0 + srow) * Kdim + scol;
  u16* AsP = As + srow * 32 + scol;
  u16* BsP = Bs + srow * 32 + scol;

  for (int k0 = 0; k0 < Kdim; k0 += 32) {
    gl_lds16(Ag + k0, AsP);
    gl_lds16(Ag + k0 + (size_t)64 * Kdim, AsP + 64 * 32);
    gl_lds16(Bg + k0, BsP);
    __syncthreads();
    short8 a[2], b[4];
#pragma unroll
    for (int m = 0; m < 2; ++m)
      a[m] = *(const short8*)(As + (wid * 32 + m * 16 + lr) * 32 + lk * 8);
#pragma unroll
    for (int n = 0; n < 4; ++n)
      b[n] = *(const short8*)(Bs + (n * 16 + lr) * 32 + lk * 8);
#pragma unroll
    for (int m = 0; m < 2; ++m)
#pragma unroll
      for (int n = 0; n < 4; ++n)
        acc[m][n] = __builtin_amdgcn_mfma_f32_16x16x32_bf16(a[m], b[n], acc[m][n], 0, 0, 0);
    __syncthreads();
  }

#pragma unroll
  for (int m = 0; m < 2; ++m)
#pragma unroll
    for (int n = 0; n < 4; ++n)
#pragma unroll
      for (int i = 0; i < 4; ++i) {
        int r = bm0 + wid * 32 + m * 16 + lk * 4 + i;
        int c = bn0 + n * 16 + lr;
        float v = acc[m][n][i];
        if (EPI == 0) {
          Cf[(size_t)r * Ndim + c] = v;
        } else {
          v += bias[c];
          v = v / (1.f + expf(-v));
          Cb[(size_t)r * Ndim + c] = f2bf(v);
        }
      }
}

// ---------------- fused gate+up: actS[t, e*F+f] = comb[t,e]*silu(g)*u ----------------
// grid.x: 256 strips (e, f0=64-wide), grid.y: 2 token halves (1024 each).
// Block tile: 256 tokens x (64 gate + 64 up), BK=32. 4 waves, 64 rows each.
template<bool PRECVT>
__global__ __launch_bounds__(256, 2)
void k_gateup(const u16* __restrict__ Xbf, const void* __restrict__ Wg_,
              const void* __restrict__ Wu_, const float* __restrict__ comb,
              u16* __restrict__ actS)
{
  __shared__ __align__(16) u16 As[256 * 32];
  __shared__ __align__(16) u16 Gs[64 * 32];
  __shared__ __align__(16) u16 Us[64 * 32];
  const int tid = threadIdx.x;
  const int e  = blockIdx.x >> 4;
  const int f0 = (blockIdx.x & 15) * 64;
  const int tbase = blockIdx.y * 1024;
  const int wid = tid >> 6, lane = tid & 63;
  const int lr = lane & 15, lk = lane >> 4;
  const int srow = tid >> 2, scol = (tid & 3) * 8;
  const int mrow = wid * 64;

  const size_t brow_off = (size_t)(e * F_DIM + f0 + srow) * H_DIM + scol;
  f32x4 zero4 = {0.f, 0.f, 0.f, 0.f};

  for (int t0 = tbase; t0 < tbase + 1024; t0 += 256) {
    f32x4 acc[4][8];
#pragma unroll
    for (int m = 0; m < 4; ++m)
#pragma unroll
      for (int n = 0; n < 8; ++n) acc[m][n] = zero4;

    const u16* Ag = Xbf + (size_t)(t0 + srow) * H_DIM + scol;
    u16* AsP = As + srow * 32 + scol;

    for (int k0 = 0; k0 < H_DIM; k0 += 32) {
#pragma unroll
      for (int j = 0; j < 4; ++j)
        gl_lds16(Ag + k0 + (size_t)(j * 64) * H_DIM, AsP + j * 64 * 32);
      if (PRECVT) {
        const u16* G  = (const u16*)Wg_;
        const u16* Uw = (const u16*)Wu_;
        gl_lds16(G  + brow_off + k0, Gs + srow * 32 + scol);
        gl_lds16(Uw + brow_off + k0, Us + srow * 32 + scol);
      } else {
        const float* G  = (const float*)Wg_ + brow_off + k0;
        const float* Uw = (const float*)Wu_ + brow_off + k0;
        float4 g0 = *(const float4*)G,  g1 = *(const float4*)(G + 4);
        float4 u0 = *(const float4*)Uw, u1 = *(const float4*)(Uw + 4);
        union { short8 v; u16 ee[8]; } og, ou;
        og.ee[0] = f2bf(g0.x); og.ee[1] = f2bf(g0.y); og.ee[2] = f2bf(g0.z); og.ee[3] = f2bf(g0.w);
        og.ee[4] = f2bf(g1.x); og.ee[5] = f2bf(g1.y); og.ee[6] = f2bf(g1.z); og.ee[7] = f2bf(g1.w);
        ou.ee[0] = f2bf(u0.x); ou.ee[1] = f2bf(u0.y); ou.ee[2] = f2bf(u0.z); ou.ee[3] = f2bf(u0.w);
        ou.ee[4] = f2bf(u1.x); ou.ee[5] = f2bf(u1.y); ou.ee[6] = f2bf(u1.z); ou.ee[7] = f2bf(u1.w);
        *(short8*)(Gs + srow * 32 + scol) = og.v;
        *(short8*)(Us + srow * 32 + scol) = ou.v;
      }
      __syncthreads();
      short8 a[4], bg[4], bu[4];
#pragma unroll
      for (int m = 0; m < 4; ++m)
        a[m] = *(const short8*)(As + (mrow + m * 16 + lr) * 32 + lk * 8);
#pragma unroll
      for (int n = 0; n < 4; ++n) {
        bg[n] = *(const short8*)(Gs + (n * 16 + lr) * 32 + lk * 8);
        bu[n] = *(const short8*)(Us + (n * 16 + lr) * 32 + lk * 8);
      }
#pragma unroll
      for (int m = 0; m < 4; ++m)
#pragma unroll
        for (int n = 0; n < 4; ++n) {
          acc[m][n]     = __builtin_amdgcn_mfma_f32_16x16x32_bf16(a[m], bg[n], acc[m][n], 0, 0, 0);
          acc[m][n + 4] = __builtin_amdgcn_mfma_f32_16x16x32_bf16(a[m], bu[n], acc[m][n + 4], 0, 0, 0);
        }
      __syncthreads();
    }
#pragma unroll
    for (int m = 0; m < 4; ++m)
#pragma unroll
      for (int n = 0; n < 4; ++n)
#pragma unroll
        for (int i = 0; i < 4; ++i) {
          int t = t0 + mrow + m * 16 + lk * 4 + i;
          int f = f0 + n * 16 + lr;
          float g = acc[m][n][i], u = acc[m][n + 4][i];
          float c = comb[t * E_NUM + e];
          float act = c * (g / (1.f + expf(-g))) * u;
          actS[(size_t)t * EFD + e * F_DIM + f] = f2bf(act);
        }
  }
}

// ---------------- per-token router: z-pred + gumbel argmax + softmax + top-8 ----------------
__global__ void k_router(const float* __restrict__ x, const float* __restrict__ gu,
                         const u16* __restrict__ h1, const float* __restrict__ W2,
                         const float* __restrict__ b2, const float* __restrict__ gw,
                         const float* __restrict__ Umat, const float* __restrict__ alpha_p,
                         float* __restrict__ comb)
{
  __shared__ float xs[H_DIM];
  __shared__ float zbuf[8];
  __shared__ float rl[16];
  __shared__ int zi_s;
  const int t = blockIdx.x, tid = threadIdx.x;

  for (int i = tid; i < H_DIM / 4; i += 256)
    ((float4*)xs)[i] = ((const float4*)(x + (size_t)t * H_DIM))[i];

  int zg = tid >> 5, l32 = tid & 31;
  float zp = 0.f;
  const u16* h1r = h1 + (size_t)t * M_DIM;
  for (int j = l32; j < M_DIM; j += 32)
    zp += bf2f(h1r[j]) * W2[zg * M_DIM + j];
#pragma unroll
  for (int off = 16; off; off >>= 1) zp += __shfl_xor(zp, off);
  if (l32 == 0) zbuf[zg] = zp + b2[zg];
  __syncthreads();
  if (tid == 0) {
    float best = -1e30f; int bi = 0;
#pragma unroll
    for (int z = 0; z < 8; ++z) {
      float u = gu[t * 8 + z];
      float g = -logf(-logf(u + 1e-10f) + 1e-10f);
      float v = zbuf[z] + g;
      if (v > best) { best = v; bi = z; }
    }
    zi_s = bi;
  }
  __syncthreads();
  int eg = tid >> 4, l16 = tid & 15;
  float rp = 0.f;
  const float* gwr = gw + (size_t)eg * H_DIM;
  for (int j = l16; j < H_DIM; j += 16) rp += xs[j] * gwr[j];
#pragma unroll
  for (int off = 8; off; off >>= 1) rp += __shfl_xor(rp, off);
  if (l16 == 0) rl[eg] = rp;
  __syncthreads();
  if (tid == 0) {
    float a = alpha_p[0]; int zi = zi_s;
    float w[16], mx = -1e30f;
#pragma unroll
    for (int e = 0; e < 16; ++e) { w[e] = rl[e] + a * Umat[zi * 16 + e]; mx = fmaxf(mx, w[e]); }
    float s = 0.f;
#pragma unroll
    for (int e = 0; e < 16; ++e) { w[e] = expf(w[e] - mx); s += w[e]; }
    float inv = 1.f / s;
    unsigned chosen = 0;
#pragma unroll
    for (int k = 0; k < 8; ++k) {
      float bw = -1.f; int bi = 0;
      for (int e = 0; e < 16; ++e)
        if (!((chosen >> e) & 1u) && w[e] > bw) { bw = w[e]; bi = e; }
      chosen |= 1u << bi;
    }
    for (int e = 0; e < 16; ++e)
      comb[t * 16 + e] = ((chosen >> e) & 1u) ? w[e] * inv : 0.f;
  }
}

extern "C" void kernel_launch(void* const* d_in, const int* in_sizes, int n_in,
                              void* d_out, int out_size, void* d_ws, size_t ws_size,
                              hipStream_t stream)
{
  const float* x  = (const float*)d_in[0];
  const float* gu = (const float*)d_in[1];
  const float* W1 = (const float*)d_in[2];
  const float* b1 = (const float*)d_in[3];
  const float* W2 = (const float*)d_in[4];
  const float* b2 = (const float*)d_in[5];
  const float* gw = (const float*)d_in[6];
  const float* Um = (const float*)d_in[7];
  const float* al = (const float*)d_in[8];
  const float* Wg = (const float*)d_in[9];
  const float* Wu = (const float*)d_in[10];
  const float* Wd = (const float*)d_in[11];
  float* y = (float*)d_out;

  size_t off = 0;
  char* base = (char*)d_ws;
  auto take = [&](size_t b) { char* p = base + off; off += (b + 255) & ~(size_t)255; return p; };
  u16*  x_bf  = (u16*)take((size_t)T_TOK * H_DIM * 2);
  u16*  W1_bf = (u16*)take((size_t)M_DIM * H_DIM * 2);
  u16*  h1_bf = (u16*)take((size_t)T_TOK * M_DIM * 2);
  u16*  Wdp   = (u16*)take((size_t)H_DIM * EFD * 2);
  u16*  actS  = (u16*)take((size_t)T_TOK * EFD * 2);
  float* comb = (float*)take((size_t)T_TOK * E_NUM * 4);
  u16*  Wg_bf = (u16*)take((size_t)E_NUM * F_DIM * H_DIM * 2);
  u16*  Wu_bf = (u16*)take((size_t)E_NUM * F_DIM * H_DIM * 2);
  bool precvt = (off <= ws_size);

  k_cvt<<<dim3((T_TOK * H_DIM / 8) / 256), 256, 0, stream>>>(x, x_bf, T_TOK * H_DIM / 8);
  k_cvt<<<dim3((M_DIM * H_DIM / 8) / 256), 256, 0, stream>>>(W1, W1_bf, M_DIM * H_DIM / 8);
  k_cvt_wd<<<dim3((E_NUM * H_DIM * F_DIM / 8) / 256), 256, 0, stream>>>(Wd, Wdp);
  if (precvt) {
    k_cvt<<<dim3(16384), 256, 0, stream>>>(Wg, Wg_bf, E_NUM * F_DIM * H_DIM / 8);
    k_cvt<<<dim3(16384), 256, 0, stream>>>(Wu, Wu_bf, E_NUM * F_DIM * H_DIM / 8);
  }

  // h1 = silu(x @ W1^T + b1)  -> bf16
  k_gemm<1><<<dim3(M_DIM / 64, T_TOK / 128), 256, 0, stream>>>(x_bf, W1_bf, M_DIM, H_DIM,
                                                               nullptr, h1_bf, b1);
  k_router<<<dim3(T_TOK), 256, 0, stream>>>(x, gu, h1_bf, W2, b2, gw, Um, al, comb);

  if (precvt)
    k_gateup<true><<<dim3(256, 2), 256, 0, stream>>>(x_bf, Wg_bf, Wu_bf, comb, actS);
  else
    k_gateup<false><<<dim3(256, 2), 256, 0, stream>>>(x_bf, Wg, Wu, comb, actS);

  // y = actS @ Wdp^T  (K = E*F = 16384) -> fp32 out
  k_gemm<0><<<dim3(H_DIM / 64, T_TOK / 128), 256, 0, stream>>>(actS, Wdp, H_DIM, EFD,
                                                               y, nullptr, nullptr);
}

// Round 2
// 794.955 us; speedup vs baseline: 1.0593x; 1.0593x over previous
//
#include <hip/hip_runtime.h>
#include <math.h>

typedef unsigned short u16;
typedef __attribute__((ext_vector_type(8))) short short8;
typedef __attribute__((ext_vector_type(4))) float f32x4;

#define T_TOK 2048
#define H_DIM 2048
#define E_NUM 16
#define F_DIM 1024
#define EFD   16384
#define M_DIM 512

__device__ __forceinline__ u16 f2bf(float x) {
  union { float f; unsigned u; } c; c.f = x;
  unsigned r = c.u + 0x7FFFu + ((c.u >> 16) & 1u);   // RNE
  return (u16)(r >> 16);
}
__device__ __forceinline__ float bf2f(u16 h) {
  union { unsigned u; float f; } c; c.u = ((unsigned)h) << 16;
  return c.f;
}
__device__ __forceinline__ void gl_lds16(const void* g, void* l) {
  __builtin_amdgcn_global_load_lds((const __attribute__((address_space(1))) void*)g,
                                   (__attribute__((address_space(3))) void*)l, 16, 0, 0);
}

// ---------------- conversion kernels ----------------
__global__ void k_cvt(const float* __restrict__ s, u16* __restrict__ d, int n8) {
  int i = blockIdx.x * 256 + threadIdx.x;
  if (i >= n8) return;
  const float4* sp = (const float4*)(s + (size_t)i * 8);
  float4 a = sp[0], b = sp[1];
  union { short8 v; u16 e[8]; } o;
  o.e[0] = f2bf(a.x); o.e[1] = f2bf(a.y); o.e[2] = f2bf(a.z); o.e[3] = f2bf(a.w);
  o.e[4] = f2bf(b.x); o.e[5] = f2bf(b.y); o.e[6] = f2bf(b.z); o.e[7] = f2bf(b.w);
  *(short8*)(d + (size_t)i * 8) = o.v;
}

// Wd[e,h,f] -> Wdp[h, e*F+f] (bf16)
__global__ void k_cvt_wd(const float* __restrict__ wd, u16* __restrict__ wdp) {
  int i = blockIdx.x * 256 + threadIdx.x;          // over E*H*F/8
  if (i >= (E_NUM * H_DIM * F_DIM) / 8) return;
  int f8 = i & 127;                                 // F/8 = 128
  int h  = (i >> 7) & (H_DIM - 1);
  int e  = i >> 18;
  const float4* sp = (const float4*)(wd + (size_t)(e * H_DIM + h) * F_DIM + f8 * 8);
  float4 a = sp[0], b = sp[1];
  union { short8 v; u16 ee[8]; } o;
  o.ee[0] = f2bf(a.x); o.ee[1] = f2bf(a.y); o.ee[2] = f2bf(a.z); o.ee[3] = f2bf(a.w);
  o.ee[4] = f2bf(b.x); o.ee[5] = f2bf(b.y); o.ee[6] = f2bf(b.z); o.ee[7] = f2bf(b.w);
  *(short8*)(wdp + (size_t)h * EFD + e * F_DIM + f8 * 8) = o.v;
}

// ---------------- small GEMM for h1: C[M,N] = silu(A[M,K] * B[N,K]^T + bias) ----------------
// BM=128, BN=64, BK=32. 4 waves stacked along M (32 rows each).
__global__ __launch_bounds__(256, 2)
void k_gemm_h1(const u16* __restrict__ A, const u16* __restrict__ B, int Ndim, int Kdim,
               u16* __restrict__ Cb, const float* __restrict__ bias)
{
  __shared__ __align__(16) u16 As[128 * 32];
  __shared__ __align__(16) u16 Bs[64 * 32];
  const int tid = threadIdx.x;
  const int bm0 = blockIdx.y * 128;
  const int bn0 = blockIdx.x * 64;
  const int wid = tid >> 6, lane = tid & 63;
  const int lr = lane & 15, lk = lane >> 4;
  const int srow = tid >> 2, scol = (tid & 3) * 8;

  f32x4 zero4 = {0.f, 0.f, 0.f, 0.f};
  f32x4 acc[2][4];
#pragma unroll
  for (int m = 0; m < 2; ++m)
#pragma unroll
    for (int n = 0; n < 4; ++n) acc[m][n] = zero4;

  const u16* Ag = A + (size_t)(bm0 + srow) * Kdim + scol;
  const u16* Bg = B + (size_t)(bn0 + srow) * Kdim + scol;
  u16* AsP = As + srow * 32 + scol;
  u16* BsP = Bs + srow * 32 + scol;

  for (int k0 = 0; k0 < Kdim; k0 += 32) {
    gl_lds16(Ag + k0, AsP);
    gl_lds16(Ag + k0 + (size_t)64 * Kdim, AsP + 64 * 32);
    gl_lds16(Bg + k0, BsP);
    __syncthreads();
    short8 a[2], b[4];
#pragma unroll
    for (int m = 0; m < 2; ++m)
      a[m] = *(const short8*)(As + (wid * 32 + m * 16 + lr) * 32 + lk * 8);
#pragma unroll
    for (int n = 0; n < 4; ++n)
      b[n] = *(const short8*)(Bs + (n * 16 + lr) * 32 + lk * 8);
#pragma unroll
    for (int m = 0; m < 2; ++m)
#pragma unroll
      for (int n = 0; n < 4; ++n)
        acc[m][n] = __builtin_amdgcn_mfma_f32_16x16x32_bf16(a[m], b[n], acc[m][n], 0, 0, 0);
    __syncthreads();
  }

#pragma unroll
  for (int m = 0; m < 2; ++m)
#pragma unroll
    for (int n = 0; n < 4; ++n)
#pragma unroll
      for (int i = 0; i < 4; ++i) {
        int r = bm0 + wid * 32 + m * 16 + lk * 4 + i;
        int c = bn0 + n * 16 + lr;
        float v = acc[m][n][i] + bias[c];
        v = v / (1.f + expf(-v));
        Cb[(size_t)r * Ndim + c] = f2bf(v);
      }
}

// ---------------- dense down-proj GEMM: y[T,H] = actS[T,EFD] * Wdp[H,EFD]^T ----------------
// m97-style: BM=BN=128, BK=32, 4 waves 2x2, each 64x64. XCD-swizzled grid (256 blocks).
__global__ __launch_bounds__(256, 2)
void k_down(const u16* __restrict__ A, const u16* __restrict__ B, float* __restrict__ C)
{
  __shared__ __align__(16) u16 As[128 * 32];
  __shared__ __align__(16) u16 Bs[128 * 32];
  const int bid = blockIdx.x;
  const int swz = (bid & 7) * 32 + (bid >> 3);       // 256 % 8 == 0: bijective
  const int bm0 = (swz >> 4) * 128;
  const int bn0 = (swz & 15) * 128;
  const int tid = threadIdx.x;
  const int wid = tid >> 6, lane = tid & 63;
  const int wr = (wid >> 1) * 64, wc = (wid & 1) * 64;
  const int lr = lane & 15, lk = lane >> 4;
  const int srow = tid >> 2, scol = (tid & 3) * 8;

  f32x4 zero4 = {0.f, 0.f, 0.f, 0.f};
  f32x4 acc[4][4];
#pragma unroll
  for (int m = 0; m < 4; ++m)
#pragma unroll
    for (int n = 0; n < 4; ++n) acc[m][n] = zero4;

  const u16* Ag = A + (size_t)(bm0 + srow) * EFD + scol;
  const u16* Bg = B + (size_t)(bn0 + srow) * EFD + scol;
  u16* AsP = As + srow * 32 + scol;
  u16* BsP = Bs + srow * 32 + scol;

  for (int k0 = 0; k0 < EFD; k0 += 32) {
    gl_lds16(Ag + k0, AsP);
    gl_lds16(Ag + k0 + (size_t)64 * EFD, AsP + 64 * 32);
    gl_lds16(Bg + k0, BsP);
    gl_lds16(Bg + k0 + (size_t)64 * EFD, BsP + 64 * 32);
    __syncthreads();
    short8 a[4], b[4];
#pragma unroll
    for (int m = 0; m < 4; ++m)
      a[m] = *(const short8*)(As + (wr + m * 16 + lr) * 32 + lk * 8);
#pragma unroll
    for (int n = 0; n < 4; ++n)
      b[n] = *(const short8*)(Bs + (wc + n * 16 + lr) * 32 + lk * 8);
#pragma unroll
    for (int m = 0; m < 4; ++m)
#pragma unroll
      for (int n = 0; n < 4; ++n)
        acc[m][n] = __builtin_amdgcn_mfma_f32_16x16x32_bf16(a[m], b[n], acc[m][n], 0, 0, 0);
    __syncthreads();
  }

#pragma unroll
  for (int m = 0; m < 4; ++m)
#pragma unroll
    for (int n = 0; n < 4; ++n)
#pragma unroll
      for (int i = 0; i < 4; ++i) {
        int r = bm0 + wr + m * 16 + lk * 4 + i;
        int c = bn0 + wc + n * 16 + lr;
        C[(size_t)r * H_DIM + c] = acc[m][n][i];
      }
}

// ---------------- sparse gate+up: per active (token,expert) pair ----------------
// grid: (F/128 strips, 16 token-blocks, 16 experts). Block: 128 tokens x 128 f,
// computes BOTH gate and up (three LDS stages), epilogue scatters w*silu(g)*u.
template<bool PRECVT>
__global__ __launch_bounds__(256, 2)
void k_gu(const u16* __restrict__ Xbf, const void* __restrict__ Wg_, const void* __restrict__ Wu_,
          const int* __restrict__ list, const float* __restrict__ wlist,
          const int* __restrict__ counts, u16* __restrict__ actS)
{
  __shared__ __align__(16) u16 As[128 * 32];
  __shared__ __align__(16) u16 Gs[128 * 32];
  __shared__ __align__(16) u16 Us[128 * 32];
  const int e  = blockIdx.z;
  const int tb = blockIdx.y;
  if (tb * 128 >= counts[e]) return;                 // uniform early-exit
  const int f0 = blockIdx.x * 128;
  const int tid = threadIdx.x;
  const int wid = tid >> 6, lane = tid & 63;
  const int wr = (wid >> 1) * 64, wc = (wid & 1) * 64;
  const int lr = lane & 15, lk = lane >> 4;
  const int srow = tid >> 2, scol = (tid & 3) * 8;
  const int lbase = e * T_TOK + tb * 128;

  const int t0i = list[lbase + srow];
  const int t1i = list[lbase + 64 + srow];
  const u16* Ag0 = Xbf + (size_t)t0i * H_DIM + scol;
  const u16* Ag1 = Xbf + (size_t)t1i * H_DIM + scol;
  const size_t wrow = (size_t)(e * F_DIM + f0 + srow) * H_DIM + scol;

  f32x4 zero4 = {0.f, 0.f, 0.f, 0.f};
  f32x4 accg[4][4], accu[4][4];
#pragma unroll
  for (int m = 0; m < 4; ++m)
#pragma unroll
    for (int n = 0; n < 4; ++n) { accg[m][n] = zero4; accu[m][n] = zero4; }

  for (int k0 = 0; k0 < H_DIM; k0 += 32) {
    gl_lds16(Ag0 + k0, As + srow * 32 + scol);
    gl_lds16(Ag1 + k0, As + (64 + srow) * 32 + scol);
    if (PRECVT) {
      const u16* G  = (const u16*)Wg_;
      const u16* Uw = (const u16*)Wu_;
      gl_lds16(G  + wrow + k0,                        Gs + srow * 32 + scol);
      gl_lds16(G  + wrow + (size_t)64 * H_DIM + k0,   Gs + (64 + srow) * 32 + scol);
      gl_lds16(Uw + wrow + k0,                        Us + srow * 32 + scol);
      gl_lds16(Uw + wrow + (size_t)64 * H_DIM + k0,   Us + (64 + srow) * 32 + scol);
    } else {
      const float* G  = (const float*)Wg_;
      const float* Uw = (const float*)Wu_;
#pragma unroll
      for (int half = 0; half < 2; ++half) {
        size_t off = wrow + (size_t)(half * 64) * H_DIM + k0;
        float4 g0 = *(const float4*)(G + off),  g1 = *(const float4*)(G + off + 4);
        float4 u0 = *(const float4*)(Uw + off), u1 = *(const float4*)(Uw + off + 4);
        union { short8 v; u16 ee[8]; } og, ou;
        og.ee[0] = f2bf(g0.x); og.ee[1] = f2bf(g0.y); og.ee[2] = f2bf(g0.z); og.ee[3] = f2bf(g0.w);
        og.ee[4] = f2bf(g1.x); og.ee[5] = f2bf(g1.y); og.ee[6] = f2bf(g1.z); og.ee[7] = f2bf(g1.w);
        ou.ee[0] = f2bf(u0.x); ou.ee[1] = f2bf(u0.y); ou.ee[2] = f2bf(u0.z); ou.ee[3] = f2bf(u0.w);
        ou.ee[4] = f2bf(u1.x); ou.ee[5] = f2bf(u1.y); ou.ee[6] = f2bf(u1.z); ou.ee[7] = f2bf(u1.w);
        *(short8*)(Gs + (half * 64 + srow) * 32 + scol) = og.v;
        *(short8*)(Us + (half * 64 + srow) * 32 + scol) = ou.v;
      }
    }
    __syncthreads();
    short8 a[4], bg[4], bu[4];
#pragma unroll
    for (int m = 0; m < 4; ++m)
      a[m] = *(const short8*)(As + (wr + m * 16 + lr) * 32 + lk * 8);
#pragma unroll
    for (int n = 0; n < 4; ++n) {
      bg[n] = *(const short8*)(Gs + (wc + n * 16 + lr) * 32 + lk * 8);
      bu[n] = *(const short8*)(Us + (wc + n * 16 + lr) * 32 + lk * 8);
    }
#pragma unroll
    for (int m = 0; m < 4; ++m)
#pragma unroll
      for (int n = 0; n < 4; ++n) {
        accg[m][n] = __builtin_amdgcn_mfma_f32_16x16x32_bf16(a[m], bg[n], accg[m][n], 0, 0, 0);
        accu[m][n] = __builtin_amdgcn_mfma_f32_16x16x32_bf16(a[m], bu[n], accu[m][n], 0, 0, 0);
      }
    __syncthreads();
  }

#pragma unroll
  for (int m = 0; m < 4; ++m)
#pragma unroll
    for (int i = 0; i < 4; ++i) {
      int slot = tb * 128 + wr + m * 16 + lk * 4 + i;
      float w = wlist[e * T_TOK + slot];
      if (w > 0.f) {
        int t = list[e * T_TOK + slot];
        u16* dst = actS + (size_t)t * EFD + e * F_DIM + f0 + wc;
#pragma unroll
        for (int n = 0; n < 4; ++n) {
          float g = accg[m][n][i], u = accu[m][n][i];
          float act = w * (g / (1.f + expf(-g))) * u;
          dst[n * 16 + lr] = f2bf(act);
        }
      }
    }
}

// ---------------- per-token router ----------------
__global__ void k_router(const float* __restrict__ x, const float* __restrict__ gu,
                         const u16* __restrict__ h1, const float* __restrict__ W2,
                         const float* __restrict__ b2, const float* __restrict__ gw,
                         const float* __restrict__ Umat, const float* __restrict__ alpha_p,
                         float* __restrict__ comb)
{
  __shared__ float xs[H_DIM];
  __shared__ float zbuf[8];
  __shared__ float rl[16];
  __shared__ int zi_s;
  const int t = blockIdx.x, tid = threadIdx.x;

  for (int i = tid; i < H_DIM / 4; i += 256)
    ((float4*)xs)[i] = ((const float4*)(x + (size_t)t * H_DIM))[i];

  int zg = tid >> 5, l32 = tid & 31;
  float zp = 0.f;
  const u16* h1r = h1 + (size_t)t * M_DIM;
  for (int j = l32; j < M_DIM; j += 32)
    zp += bf2f(h1r[j]) * W2[zg * M_DIM + j];
#pragma unroll
  for (int off = 16; off; off >>= 1) zp += __shfl_xor(zp, off);
  if (l32 == 0) zbuf[zg] = zp + b2[zg];
  __syncthreads();
  if (tid == 0) {
    float best = -1e30f; int bi = 0;
#pragma unroll
    for (int z = 0; z < 8; ++z) {
      float u = gu[t * 8 + z];
      float g = -logf(-logf(u + 1e-10f) + 1e-10f);
      float v = zbuf[z] + g;
      if (v > best) { best = v; bi = z; }
    }
    zi_s = bi;
  }
  __syncthreads();
  int eg = tid >> 4, l16 = tid & 15;
  float rp = 0.f;
  const float* gwr = gw + (size_t)eg * H_DIM;
  for (int j = l16; j < H_DIM; j += 16) rp += xs[j] * gwr[j];
#pragma unroll
  for (int off = 8; off; off >>= 1) rp += __shfl_xor(rp, off);
  if (l16 == 0) rl[eg] = rp;
  __syncthreads();
  if (tid == 0) {
    float a = alpha_p[0]; int zi = zi_s;
    float w[16], mx = -1e30f;
#pragma unroll
    for (int e = 0; e < 16; ++e) { w[e] = rl[e] + a * Umat[zi * 16 + e]; mx = fmaxf(mx, w[e]); }
    float s = 0.f;
#pragma unroll
    for (int e = 0; e < 16; ++e) { w[e] = expf(w[e] - mx); s += w[e]; }
    float inv = 1.f / s;
    unsigned chosen = 0;
#pragma unroll
    for (int k = 0; k < 8; ++k) {
      float bw = -1.f; int bi = 0;
      for (int e = 0; e < 16; ++e)
        if (!((chosen >> e) & 1u) && w[e] > bw) { bw = w[e]; bi = e; }
      chosen |= 1u << bi;
    }
    for (int e = 0; e < 16; ++e)
      comb[t * 16 + e] = ((chosen >> e) & 1u) ? w[e] * inv : 0.f;
  }
}

// ---------------- deterministic per-expert compaction (scan, no atomics) ----------------
__global__ void k_compact(const float* __restrict__ comb, int* __restrict__ list,
                          float* __restrict__ wlist, int* __restrict__ counts)
{
  __shared__ int sc[256];
  const int e = blockIdx.x, tid = threadIdx.x;
  int toks[8]; float ws[8]; int cnt = 0;
#pragma unroll
  for (int i = 0; i < 8; ++i) {
    int t = tid * 8 + i;
    float w = comb[t * E_NUM + e];
    if (w > 0.f) { toks[cnt] = t; ws[cnt] = w; ++cnt; }
  }
  sc[tid] = cnt;
  __syncthreads();
  for (int off = 1; off < 256; off <<= 1) {
    int v = (tid >= off) ? sc[tid - off] : 0;
    __syncthreads();
    sc[tid] += v;
    __syncthreads();
  }
  int base = sc[tid] - cnt;
  int total = sc[255];
  int padded = (total + 127) & ~127;
  int* lp = list + e * T_TOK;
  float* wp = wlist + e * T_TOK;
  for (int j = 0; j < cnt; ++j) { lp[base + j] = toks[j]; wp[base + j] = ws[j]; }
  for (int j = total + tid; j < padded; j += 256) { lp[j] = 0; wp[j] = 0.f; }
  if (tid == 0) counts[e] = padded;
}

extern "C" void kernel_launch(void* const* d_in, const int* in_sizes, int n_in,
                              void* d_out, int out_size, void* d_ws, size_t ws_size,
                              hipStream_t stream)
{
  const float* x  = (const float*)d_in[0];
  const float* gu = (const float*)d_in[1];
  const float* W1 = (const float*)d_in[2];
  const float* b1 = (const float*)d_in[3];
  const float* W2 = (const float*)d_in[4];
  const float* b2 = (const float*)d_in[5];
  const float* gw = (const float*)d_in[6];
  const float* Um = (const float*)d_in[7];
  const float* al = (const float*)d_in[8];
  const float* Wg = (const float*)d_in[9];
  const float* Wu = (const float*)d_in[10];
  const float* Wd = (const float*)d_in[11];
  float* y = (float*)d_out;

  size_t off = 0;
  char* base = (char*)d_ws;
  auto take = [&](size_t b) { char* p = base + off; off += (b + 255) & ~(size_t)255; return p; };
  u16*   x_bf   = (u16*)take((size_t)T_TOK * H_DIM * 2);
  u16*   W1_bf  = (u16*)take((size_t)M_DIM * H_DIM * 2);
  u16*   h1_bf  = (u16*)take((size_t)T_TOK * M_DIM * 2);
  u16*   Wdp    = (u16*)take((size_t)H_DIM * EFD * 2);
  u16*   actS   = (u16*)take((size_t)T_TOK * EFD * 2);
  float* comb   = (float*)take((size_t)T_TOK * E_NUM * 4);
  int*   list   = (int*)take((size_t)E_NUM * T_TOK * 4);
  float* wlist  = (float*)take((size_t)E_NUM * T_TOK * 4);
  int*   counts = (int*)take(64 * 4);
  u16*   Wg_bf  = (u16*)take((size_t)E_NUM * F_DIM * H_DIM * 2);
  u16*   Wu_bf  = (u16*)take((size_t)E_NUM * F_DIM * H_DIM * 2);
  bool precvt = (off <= ws_size);

  // zero actS: inactive (t,e) slices must be 0 for the dense down-proj
  hipMemsetAsync(actS, 0, (size_t)T_TOK * EFD * 2, stream);

  k_cvt<<<dim3((T_TOK * H_DIM / 8) / 256), 256, 0, stream>>>(x, x_bf, T_TOK * H_DIM / 8);
  k_cvt<<<dim3((M_DIM * H_DIM / 8) / 256), 256, 0, stream>>>(W1, W1_bf, M_DIM * H_DIM / 8);
  k_cvt_wd<<<dim3((E_NUM * H_DIM * F_DIM / 8) / 256), 256, 0, stream>>>(Wd, Wdp);
  if (precvt) {
    k_cvt<<<dim3(16384), 256, 0, stream>>>(Wg, Wg_bf, E_NUM * F_DIM * H_DIM / 8);
    k_cvt<<<dim3(16384), 256, 0, stream>>>(Wu, Wu_bf, E_NUM * F_DIM * H_DIM / 8);
  }

  // h1 = silu(x @ W1^T + b1) -> bf16
  k_gemm_h1<<<dim3(M_DIM / 64, T_TOK / 128), 256, 0, stream>>>(x_bf, W1_bf, M_DIM, H_DIM,
                                                               h1_bf, b1);
  k_router<<<dim3(T_TOK), 256, 0, stream>>>(x, gu, h1_bf, W2, b2, gw, Um, al, comb);
  k_compact<<<dim3(E_NUM), 256, 0, stream>>>(comb, list, wlist, counts);

  if (precvt)
    k_gu<true><<<dim3(F_DIM / 128, 16, E_NUM), 256, 0, stream>>>(x_bf, Wg_bf, Wu_bf,
                                                                 list, wlist, counts, actS);
  else
    k_gu<false><<<dim3(F_DIM / 128, 16, E_NUM), 256, 0, stream>>>(x_bf, Wg, Wu,
                                                                  list, wlist, counts, actS);

  // y = actS @ Wdp^T  (dense, K=16384; zeros for unselected experts)
  k_down<<<dim3(256), 256, 0, stream>>>(actS, Wdp, y);
}

// Round 3
// 646.826 us; speedup vs baseline: 1.3019x; 1.2290x over previous
//
#include <hip/hip_runtime.h>
#include <math.h>

typedef unsigned short u16;
typedef __attribute__((ext_vector_type(8))) short short8;
typedef __attribute__((ext_vector_type(4))) float f32x4;

#define T_TOK 2048
#define H_DIM 2048
#define E_NUM 16
#define F_DIM 1024
#define EFD   16384
#define M_DIM 512
#define KSPLIT 4

__device__ __forceinline__ u16 f2bf(float x) {
  union { float f; unsigned u; } c; c.f = x;
  unsigned r = c.u + 0x7FFFu + ((c.u >> 16) & 1u);   // RNE
  return (u16)(r >> 16);
}
__device__ __forceinline__ float bf2f(u16 h) {
  union { unsigned u; float f; } c; c.u = ((unsigned)h) << 16;
  return c.f;
}
__device__ __forceinline__ void gl_lds16(const void* g, void* l) {
  __builtin_amdgcn_global_load_lds((const __attribute__((address_space(1))) void*)g,
                                   (__attribute__((address_space(3))) void*)l, 16, 0, 0);
}

// ---------------- conversion kernels ----------------
__global__ void k_cvt(const float* __restrict__ s, u16* __restrict__ d, int n8) {
  int i = blockIdx.x * 256 + threadIdx.x;
  if (i >= n8) return;
  const float4* sp = (const float4*)(s + (size_t)i * 8);
  float4 a = sp[0], b = sp[1];
  union { short8 v; u16 e[8]; } o;
  o.e[0] = f2bf(a.x); o.e[1] = f2bf(a.y); o.e[2] = f2bf(a.z); o.e[3] = f2bf(a.w);
  o.e[4] = f2bf(b.x); o.e[5] = f2bf(b.y); o.e[6] = f2bf(b.z); o.e[7] = f2bf(b.w);
  *(short8*)(d + (size_t)i * 8) = o.v;
}

// Wd[e,h,f] -> Wdp[h, e*F+f] (bf16)
__global__ void k_cvt_wd(const float* __restrict__ wd, u16* __restrict__ wdp) {
  int i = blockIdx.x * 256 + threadIdx.x;          // over E*H*F/8
  if (i >= (E_NUM * H_DIM * F_DIM) / 8) return;
  int f8 = i & 127;                                 // F/8 = 128
  int h  = (i >> 7) & (H_DIM - 1);
  int e  = i >> 18;
  const float4* sp = (const float4*)(wd + (size_t)(e * H_DIM + h) * F_DIM + f8 * 8);
  float4 a = sp[0], b = sp[1];
  union { short8 v; u16 ee[8]; } o;
  o.ee[0] = f2bf(a.x); o.ee[1] = f2bf(a.y); o.ee[2] = f2bf(a.z); o.ee[3] = f2bf(a.w);
  o.ee[4] = f2bf(b.x); o.ee[5] = f2bf(b.y); o.ee[6] = f2bf(b.z); o.ee[7] = f2bf(b.w);
  *(short8*)(wdp + (size_t)h * EFD + e * F_DIM + f8 * 8) = o.v;
}

// ---------------- small GEMM for h1: C = silu(A*B^T + bias) -> bf16 ----------------
__global__ __launch_bounds__(256, 2)
void k_gemm_h1(const u16* __restrict__ A, const u16* __restrict__ B, int Ndim, int Kdim,
               u16* __restrict__ Cb, const float* __restrict__ bias)
{
  __shared__ __align__(16) u16 As[128 * 32];
  __shared__ __align__(16) u16 Bs[64 * 32];
  const int tid = threadIdx.x;
  const int bm0 = blockIdx.y * 128;
  const int bn0 = blockIdx.x * 64;
  const int wid = tid >> 6, lane = tid & 63;
  const int lr = lane & 15, lk = lane >> 4;
  const int srow = tid >> 2, scol = (tid & 3) * 8;

  f32x4 zero4 = {0.f, 0.f, 0.f, 0.f};
  f32x4 acc[2][4];
#pragma unroll
  for (int m = 0; m < 2; ++m)
#pragma unroll
    for (int n = 0; n < 4; ++n) acc[m][n] = zero4;

  const u16* Ag = A + (size_t)(bm0 + srow) * Kdim + scol;
  const u16* Bg = B + (size_t)(bn0 + srow) * Kdim + scol;
  u16* AsP = As + srow * 32 + scol;
  u16* BsP = Bs + srow * 32 + scol;

  for (int k0 = 0; k0 < Kdim; k0 += 32) {
    gl_lds16(Ag + k0, AsP);
    gl_lds16(Ag + k0 + (size_t)64 * Kdim, AsP + 64 * 32);
    gl_lds16(Bg + k0, BsP);
    __syncthreads();
    short8 a[2], b[4];
#pragma unroll
    for (int m = 0; m < 2; ++m)
      a[m] = *(const short8*)(As + (wid * 32 + m * 16 + lr) * 32 + lk * 8);
#pragma unroll
    for (int n = 0; n < 4; ++n)
      b[n] = *(const short8*)(Bs + (n * 16 + lr) * 32 + lk * 8);
#pragma unroll
    for (int m = 0; m < 2; ++m)
#pragma unroll
      for (int n = 0; n < 4; ++n)
        acc[m][n] = __builtin_amdgcn_mfma_f32_16x16x32_bf16(a[m], b[n], acc[m][n], 0, 0, 0);
    __syncthreads();
  }

#pragma unroll
  for (int m = 0; m < 2; ++m)
#pragma unroll
    for (int n = 0; n < 4; ++n)
#pragma unroll
      for (int i = 0; i < 4; ++i) {
        int r = bm0 + wid * 32 + m * 16 + lk * 4 + i;
        int c = bn0 + n * 16 + lr;
        float v = acc[m][n][i] + bias[c];
        v = v / (1.f + expf(-v));
        Cb[(size_t)r * Ndim + c] = f2bf(v);
      }
}

// ---------------- split-K down-proj: partial[ks][T,H] = actS[:,Kslice] * Wdp[:,Kslice]^T ----
// BM=BN=128, BK=32, 4 waves 2x2. grid = (256 swizzled tiles, KSPLIT).
__global__ __launch_bounds__(256, 4)
void k_down_sk(const u16* __restrict__ A, const u16* __restrict__ B, float* __restrict__ P)
{
  __shared__ __align__(16) u16 As[128 * 32];
  __shared__ __align__(16) u16 Bs[128 * 32];
  const int bid = blockIdx.x;
  const int swz = (bid & 7) * 32 + (bid >> 3);       // 256 % 8 == 0: bijective
  const int bm0 = (swz >> 4) * 128;
  const int bn0 = (swz & 15) * 128;
  const int ks  = blockIdx.y;
  const int kbeg = ks * (EFD / KSPLIT), kend = kbeg + EFD / KSPLIT;
  const int tid = threadIdx.x;
  const int wid = tid >> 6, lane = tid & 63;
  const int wr = (wid >> 1) * 64, wc = (wid & 1) * 64;
  const int lr = lane & 15, lk = lane >> 4;
  const int srow = tid >> 2, scol = (tid & 3) * 8;

  f32x4 zero4 = {0.f, 0.f, 0.f, 0.f};
  f32x4 acc[4][4];
#pragma unroll
  for (int m = 0; m < 4; ++m)
#pragma unroll
    for (int n = 0; n < 4; ++n) acc[m][n] = zero4;

  const u16* Ag = A + (size_t)(bm0 + srow) * EFD + scol;
  const u16* Bg = B + (size_t)(bn0 + srow) * EFD + scol;
  u16* AsP = As + srow * 32 + scol;
  u16* BsP = Bs + srow * 32 + scol;

  for (int k0 = kbeg; k0 < kend; k0 += 32) {
    gl_lds16(Ag + k0, AsP);
    gl_lds16(Ag + k0 + (size_t)64 * EFD, AsP + 64 * 32);
    gl_lds16(Bg + k0, BsP);
    gl_lds16(Bg + k0 + (size_t)64 * EFD, BsP + 64 * 32);
    __syncthreads();
    short8 a[4], b[4];
#pragma unroll
    for (int m = 0; m < 4; ++m)
      a[m] = *(const short8*)(As + (wr + m * 16 + lr) * 32 + lk * 8);
#pragma unroll
    for (int n = 0; n < 4; ++n)
      b[n] = *(const short8*)(Bs + (wc + n * 16 + lr) * 32 + lk * 8);
#pragma unroll
    for (int m = 0; m < 4; ++m)
#pragma unroll
      for (int n = 0; n < 4; ++n)
        acc[m][n] = __builtin_amdgcn_mfma_f32_16x16x32_bf16(a[m], b[n], acc[m][n], 0, 0, 0);
    __syncthreads();
  }

  float* Pk = P + (size_t)ks * T_TOK * H_DIM;
#pragma unroll
  for (int m = 0; m < 4; ++m)
#pragma unroll
    for (int n = 0; n < 4; ++n)
#pragma unroll
      for (int i = 0; i < 4; ++i) {
        int r = bm0 + wr + m * 16 + lk * 4 + i;
        int c = bn0 + wc + n * 16 + lr;
        Pk[(size_t)r * H_DIM + c] = acc[m][n][i];
      }
}

// y = sum of KSPLIT partials (float4-vectorized)
__global__ void k_reduce(const float* __restrict__ P, float* __restrict__ y) {
  int i = blockIdx.x * 256 + threadIdx.x;            // over T*H/4
  const float4* p0 = (const float4*)P;
  const size_t stride = (size_t)T_TOK * H_DIM / 4;
  float4 a = p0[i], b = p0[i + stride], c = p0[i + 2 * stride], d = p0[i + 3 * stride];
  float4 r;
  r.x = (a.x + b.x) + (c.x + d.x);
  r.y = (a.y + b.y) + (c.y + d.y);
  r.z = (a.z + b.z) + (c.z + d.z);
  r.w = (a.w + b.w) + (c.w + d.w);
  ((float4*)y)[i] = r;
}

// ---------------- dense down-proj (fallback when !precvt) ----------------
__global__ __launch_bounds__(256, 2)
void k_down(const u16* __restrict__ A, const u16* __restrict__ B, float* __restrict__ C)
{
  __shared__ __align__(16) u16 As[128 * 32];
  __shared__ __align__(16) u16 Bs[128 * 32];
  const int bid = blockIdx.x;
  const int swz = (bid & 7) * 32 + (bid >> 3);
  const int bm0 = (swz >> 4) * 128;
  const int bn0 = (swz & 15) * 128;
  const int tid = threadIdx.x;
  const int wid = tid >> 6, lane = tid & 63;
  const int wr = (wid >> 1) * 64, wc = (wid & 1) * 64;
  const int lr = lane & 15, lk = lane >> 4;
  const int srow = tid >> 2, scol = (tid & 3) * 8;

  f32x4 zero4 = {0.f, 0.f, 0.f, 0.f};
  f32x4 acc[4][4];
#pragma unroll
  for (int m = 0; m < 4; ++m)
#pragma unroll
    for (int n = 0; n < 4; ++n) acc[m][n] = zero4;

  const u16* Ag = A + (size_t)(bm0 + srow) * EFD + scol;
  const u16* Bg = B + (size_t)(bn0 + srow) * EFD + scol;
  u16* AsP = As + srow * 32 + scol;
  u16* BsP = Bs + srow * 32 + scol;

  for (int k0 = 0; k0 < EFD; k0 += 32) {
    gl_lds16(Ag + k0, AsP);
    gl_lds16(Ag + k0 + (size_t)64 * EFD, AsP + 64 * 32);
    gl_lds16(Bg + k0, BsP);
    gl_lds16(Bg + k0 + (size_t)64 * EFD, BsP + 64 * 32);
    __syncthreads();
    short8 a[4], b[4];
#pragma unroll
    for (int m = 0; m < 4; ++m)
      a[m] = *(const short8*)(As + (wr + m * 16 + lr) * 32 + lk * 8);
#pragma unroll
    for (int n = 0; n < 4; ++n)
      b[n] = *(const short8*)(Bs + (wc + n * 16 + lr) * 32 + lk * 8);
#pragma unroll
    for (int m = 0; m < 4; ++m)
#pragma unroll
      for (int n = 0; n < 4; ++n)
        acc[m][n] = __builtin_amdgcn_mfma_f32_16x16x32_bf16(a[m], b[n], acc[m][n], 0, 0, 0);
    __syncthreads();
  }

#pragma unroll
  for (int m = 0; m < 4; ++m)
#pragma unroll
    for (int n = 0; n < 4; ++n)
#pragma unroll
      for (int i = 0; i < 4; ++i) {
        int r = bm0 + wr + m * 16 + lk * 4 + i;
        int c = bn0 + wc + n * 16 + lr;
        C[(size_t)r * H_DIM + c] = acc[m][n][i];
      }
}

// ---------------- sparse gate+up (unchanged from R2) ----------------
template<bool PRECVT>
__global__ __launch_bounds__(256, 2)
void k_gu(const u16* __restrict__ Xbf, const void* __restrict__ Wg_, const void* __restrict__ Wu_,
          const int* __restrict__ list, const float* __restrict__ wlist,
          const int* __restrict__ counts, u16* __restrict__ actS)
{
  __shared__ __align__(16) u16 As[128 * 32];
  __shared__ __align__(16) u16 Gs[128 * 32];
  __shared__ __align__(16) u16 Us[128 * 32];
  const int e  = blockIdx.z;
  const int tb = blockIdx.y;
  if (tb * 128 >= counts[e]) return;
  const int f0 = blockIdx.x * 128;
  const int tid = threadIdx.x;
  const int wid = tid >> 6, lane = tid & 63;
  const int wr = (wid >> 1) * 64, wc = (wid & 1) * 64;
  const int lr = lane & 15, lk = lane >> 4;
  const int srow = tid >> 2, scol = (tid & 3) * 8;
  const int lbase = e * T_TOK + tb * 128;

  const int t0i = list[lbase + srow];
  const int t1i = list[lbase + 64 + srow];
  const u16* Ag0 = Xbf + (size_t)t0i * H_DIM + scol;
  const u16* Ag1 = Xbf + (size_t)t1i * H_DIM + scol;
  const size_t wrow = (size_t)(e * F_DIM + f0 + srow) * H_DIM + scol;

  f32x4 zero4 = {0.f, 0.f, 0.f, 0.f};
  f32x4 accg[4][4], accu[4][4];
#pragma unroll
  for (int m = 0; m < 4; ++m)
#pragma unroll
    for (int n = 0; n < 4; ++n) { accg[m][n] = zero4; accu[m][n] = zero4; }

  for (int k0 = 0; k0 < H_DIM; k0 += 32) {
    gl_lds16(Ag0 + k0, As + srow * 32 + scol);
    gl_lds16(Ag1 + k0, As + (64 + srow) * 32 + scol);
    if (PRECVT) {
      const u16* G  = (const u16*)Wg_;
      const u16* Uw = (const u16*)Wu_;
      gl_lds16(G  + wrow + k0,                        Gs + srow * 32 + scol);
      gl_lds16(G  + wrow + (size_t)64 * H_DIM + k0,   Gs + (64 + srow) * 32 + scol);
      gl_lds16(Uw + wrow + k0,                        Us + srow * 32 + scol);
      gl_lds16(Uw + wrow + (size_t)64 * H_DIM + k0,   Us + (64 + srow) * 32 + scol);
    } else {
      const float* G  = (const float*)Wg_;
      const float* Uw = (const float*)Wu_;
#pragma unroll
      for (int half = 0; half < 2; ++half) {
        size_t off = wrow + (size_t)(half * 64) * H_DIM + k0;
        float4 g0 = *(const float4*)(G + off),  g1 = *(const float4*)(G + off + 4);
        float4 u0 = *(const float4*)(Uw + off), u1 = *(const float4*)(Uw + off + 4);
        union { short8 v; u16 ee[8]; } og, ou;
        og.ee[0] = f2bf(g0.x); og.ee[1] = f2bf(g0.y); og.ee[2] = f2bf(g0.z); og.ee[3] = f2bf(g0.w);
        og.ee[4] = f2bf(g1.x); og.ee[5] = f2bf(g1.y); og.ee[6] = f2bf(g1.z); og.ee[7] = f2bf(g1.w);
        ou.ee[0] = f2bf(u0.x); ou.ee[1] = f2bf(u0.y); ou.ee[2] = f2bf(u0.z); ou.ee[3] = f2bf(u0.w);
        ou.ee[4] = f2bf(u1.x); ou.ee[5] = f2bf(u1.y); ou.ee[6] = f2bf(u1.z); ou.ee[7] = f2bf(u1.w);
        *(short8*)(Gs + (half * 64 + srow) * 32 + scol) = og.v;
        *(short8*)(Us + (half * 64 + srow) * 32 + scol) = ou.v;
      }
    }
    __syncthreads();
    short8 a[4], bg[4], bu[4];
#pragma unroll
    for (int m = 0; m < 4; ++m)
      a[m] = *(const short8*)(As + (wr + m * 16 + lr) * 32 + lk * 8);
#pragma unroll
    for (int n = 0; n < 4; ++n) {
      bg[n] = *(const short8*)(Gs + (wc + n * 16 + lr) * 32 + lk * 8);
      bu[n] = *(const short8*)(Us + (wc + n * 16 + lr) * 32 + lk * 8);
    }
#pragma unroll
    for (int m = 0; m < 4; ++m)
#pragma unroll
      for (int n = 0; n < 4; ++n) {
        accg[m][n] = __builtin_amdgcn_mfma_f32_16x16x32_bf16(a[m], bg[n], accg[m][n], 0, 0, 0);
        accu[m][n] = __builtin_amdgcn_mfma_f32_16x16x32_bf16(a[m], bu[n], accu[m][n], 0, 0, 0);
      }
    __syncthreads();
  }

#pragma unroll
  for (int m = 0; m < 4; ++m)
#pragma unroll
    for (int i = 0; i < 4; ++i) {
      int slot = tb * 128 + wr + m * 16 + lk * 4 + i;
      float w = wlist[e * T_TOK + slot];
      if (w > 0.f) {
        int t = list[e * T_TOK + slot];
        u16* dst = actS + (size_t)t * EFD + e * F_DIM + f0 + wc;
#pragma unroll
        for (int n = 0; n < 4; ++n) {
          float g = accg[m][n][i], u = accu[m][n][i];
          float act = w * (g / (1.f + expf(-g))) * u;
          dst[n * 16 + lr] = f2bf(act);
        }
      }
    }
}

// ---------------- per-token router ----------------
__global__ void k_router(const float* __restrict__ x, const float* __restrict__ gu,
                         const u16* __restrict__ h1, const float* __restrict__ W2,
                         const float* __restrict__ b2, const float* __restrict__ gw,
                         const float* __restrict__ Umat, const float* __restrict__ alpha_p,
                         float* __restrict__ comb)
{
  __shared__ float xs[H_DIM];
  __shared__ float zbuf[8];
  __shared__ float rl[16];
  __shared__ int zi_s;
  const int t = blockIdx.x, tid = threadIdx.x;

  for (int i = tid; i < H_DIM / 4; i += 256)
    ((float4*)xs)[i] = ((const float4*)(x + (size_t)t * H_DIM))[i];

  int zg = tid >> 5, l32 = tid & 31;
  float zp = 0.f;
  const u16* h1r = h1 + (size_t)t * M_DIM;
  for (int j = l32; j < M_DIM; j += 32)
    zp += bf2f(h1r[j]) * W2[zg * M_DIM + j];
#pragma unroll
  for (int off = 16; off; off >>= 1) zp += __shfl_xor(zp, off);
  if (l32 == 0) zbuf[zg] = zp + b2[zg];
  __syncthreads();
  if (tid == 0) {
    float best = -1e30f; int bi = 0;
#pragma unroll
    for (int z = 0; z < 8; ++z) {
      float u = gu[t * 8 + z];
      float g = -logf(-logf(u + 1e-10f) + 1e-10f);
      float v = zbuf[z] + g;
      if (v > best) { best = v; bi = z; }
    }
    zi_s = bi;
  }
  __syncthreads();
  int eg = tid >> 4, l16 = tid & 15;
  float rp = 0.f;
  const float* gwr = gw + (size_t)eg * H_DIM;
  for (int j = l16; j < H_DIM; j += 16) rp += xs[j] * gwr[j];
#pragma unroll
  for (int off = 8; off; off >>= 1) rp += __shfl_xor(rp, off);
  if (l16 == 0) rl[eg] = rp;
  __syncthreads();
  if (tid == 0) {
    float a = alpha_p[0]; int zi = zi_s;
    float w[16], mx = -1e30f;
#pragma unroll
    for (int e = 0; e < 16; ++e) { w[e] = rl[e] + a * Umat[zi * 16 + e]; mx = fmaxf(mx, w[e]); }
    float s = 0.f;
#pragma unroll
    for (int e = 0; e < 16; ++e) { w[e] = expf(w[e] - mx); s += w[e]; }
    float inv = 1.f / s;
    unsigned chosen = 0;
#pragma unroll
    for (int k = 0; k < 8; ++k) {
      float bw = -1.f; int bi = 0;
      for (int e = 0; e < 16; ++e)
        if (!((chosen >> e) & 1u) && w[e] > bw) { bw = w[e]; bi = e; }
      chosen |= 1u << bi;
    }
    for (int e = 0; e < 16; ++e)
      comb[t * 16 + e] = ((chosen >> e) & 1u) ? w[e] * inv : 0.f;
  }
}

// ---------------- deterministic per-expert compaction ----------------
__global__ void k_compact(const float* __restrict__ comb, int* __restrict__ list,
                          float* __restrict__ wlist, int* __restrict__ counts)
{
  __shared__ int sc[256];
  const int e = blockIdx.x, tid = threadIdx.x;
  int toks[8]; float ws[8]; int cnt = 0;
#pragma unroll
  for (int i = 0; i < 8; ++i) {
    int t = tid * 8 + i;
    float w = comb[t * E_NUM + e];
    if (w > 0.f) { toks[cnt] = t; ws[cnt] = w; ++cnt; }
  }
  sc[tid] = cnt;
  __syncthreads();
  for (int off = 1; off < 256; off <<= 1) {
    int v = (tid >= off) ? sc[tid - off] : 0;
    __syncthreads();
    sc[tid] += v;
    __syncthreads();
  }
  int base = sc[tid] - cnt;
  int total = sc[255];
  int padded = (total + 127) & ~127;
  int* lp = list + e * T_TOK;
  float* wp = wlist + e * T_TOK;
  for (int j = 0; j < cnt; ++j) { lp[base + j] = toks[j]; wp[base + j] = ws[j]; }
  for (int j = total + tid; j < padded; j += 256) { lp[j] = 0; wp[j] = 0.f; }
  if (tid == 0) counts[e] = padded;
}

extern "C" void kernel_launch(void* const* d_in, const int* in_sizes, int n_in,
                              void* d_out, int out_size, void* d_ws, size_t ws_size,
                              hipStream_t stream)
{
  const float* x  = (const float*)d_in[0];
  const float* gu = (const float*)d_in[1];
  const float* W1 = (const float*)d_in[2];
  const float* b1 = (const float*)d_in[3];
  const float* W2 = (const float*)d_in[4];
  const float* b2 = (const float*)d_in[5];
  const float* gw = (const float*)d_in[6];
  const float* Um = (const float*)d_in[7];
  const float* al = (const float*)d_in[8];
  const float* Wg = (const float*)d_in[9];
  const float* Wu = (const float*)d_in[10];
  const float* Wd = (const float*)d_in[11];
  float* y = (float*)d_out;

  size_t off = 0;
  char* base = (char*)d_ws;
  auto take = [&](size_t b) { char* p = base + off; off += (b + 255) & ~(size_t)255; return p; };
  u16*   x_bf   = (u16*)take((size_t)T_TOK * H_DIM * 2);
  u16*   W1_bf  = (u16*)take((size_t)M_DIM * H_DIM * 2);
  u16*   h1_bf  = (u16*)take((size_t)T_TOK * M_DIM * 2);
  u16*   Wdp    = (u16*)take((size_t)H_DIM * EFD * 2);
  u16*   actS   = (u16*)take((size_t)T_TOK * EFD * 2);
  float* comb   = (float*)take((size_t)T_TOK * E_NUM * 4);
  int*   list   = (int*)take((size_t)E_NUM * T_TOK * 4);
  float* wlist  = (float*)take((size_t)E_NUM * T_TOK * 4);
  int*   counts = (int*)take(64 * 4);
  u16*   Wg_bf  = (u16*)take((size_t)E_NUM * F_DIM * H_DIM * 2);
  u16*   Wu_bf  = (u16*)take((size_t)E_NUM * F_DIM * H_DIM * 2);
  bool precvt = (off <= ws_size);
  // split-K partials alias Wg_bf/Wu_bf (dead after k_gu; stream order serializes)
  float* partial = (float*)Wg_bf;

  hipMemsetAsync(actS, 0, (size_t)T_TOK * EFD * 2, stream);

  k_cvt<<<dim3((T_TOK * H_DIM / 8) / 256), 256, 0, stream>>>(x, x_bf, T_TOK * H_DIM / 8);
  k_cvt<<<dim3((M_DIM * H_DIM / 8) / 256), 256, 0, stream>>>(W1, W1_bf, M_DIM * H_DIM / 8);
  k_cvt_wd<<<dim3((E_NUM * H_DIM * F_DIM / 8) / 256), 256, 0, stream>>>(Wd, Wdp);
  if (precvt) {
    k_cvt<<<dim3(16384), 256, 0, stream>>>(Wg, Wg_bf, E_NUM * F_DIM * H_DIM / 8);
    k_cvt<<<dim3(16384), 256, 0, stream>>>(Wu, Wu_bf, E_NUM * F_DIM * H_DIM / 8);
  }

  k_gemm_h1<<<dim3(M_DIM / 64, T_TOK / 128), 256, 0, stream>>>(x_bf, W1_bf, M_DIM, H_DIM,
                                                               h1_bf, b1);
  k_router<<<dim3(T_TOK), 256, 0, stream>>>(x, gu, h1_bf, W2, b2, gw, Um, al, comb);
  k_compact<<<dim3(E_NUM), 256, 0, stream>>>(comb, list, wlist, counts);

  if (precvt)
    k_gu<true><<<dim3(F_DIM / 128, 16, E_NUM), 256, 0, stream>>>(x_bf, Wg_bf, Wu_bf,
                                                                 list, wlist, counts, actS);
  else
    k_gu<false><<<dim3(F_DIM / 128, 16, E_NUM), 256, 0, stream>>>(x_bf, Wg, Wu,
                                                                  list, wlist, counts, actS);

  if (precvt) {
    k_down_sk<<<dim3(256, KSPLIT), 256, 0, stream>>>(actS, Wdp, partial);
    k_reduce<<<dim3((T_TOK * H_DIM / 4) / 256), 256, 0, stream>>>(partial, y);
  } else {
    k_down<<<dim3(256), 256, 0, stream>>>(actS, Wdp, y);
  }
}

// Round 4
// 618.839 us; speedup vs baseline: 1.3608x; 1.0452x over previous
//
#include <hip/hip_runtime.h>
#include <math.h>

typedef unsigned short u16;
typedef __attribute__((ext_vector_type(8))) short short8;
typedef __attribute__((ext_vector_type(4))) float f32x4;

#define T_TOK 2048
#define H_DIM 2048
#define E_NUM 16
#define F_DIM 1024
#define EFD   16384
#define M_DIM 512
#define KSPLIT 4

__device__ __forceinline__ u16 f2bf(float x) {
  union { float f; unsigned u; } c; c.f = x;
  unsigned r = c.u + 0x7FFFu + ((c.u >> 16) & 1u);   // RNE
  return (u16)(r >> 16);
}
__device__ __forceinline__ float bf2f(u16 h) {
  union { unsigned u; float f; } c; c.u = ((unsigned)h) << 16;
  return c.f;
}
__device__ __forceinline__ void gl_lds16(const void* g, void* l) {
  __builtin_amdgcn_global_load_lds((const __attribute__((address_space(1))) void*)g,
                                   (__attribute__((address_space(3))) void*)l, 16, 0, 0);
}

// ---------------- conversion kernels ----------------
__global__ void k_cvt(const float* __restrict__ s, u16* __restrict__ d, int n8) {
  int i = blockIdx.x * 256 + threadIdx.x;
  if (i >= n8) return;
  const float4* sp = (const float4*)(s + (size_t)i * 8);
  float4 a = sp[0], b = sp[1];
  union { short8 v; u16 e[8]; } o;
  o.e[0] = f2bf(a.x); o.e[1] = f2bf(a.y); o.e[2] = f2bf(a.z); o.e[3] = f2bf(a.w);
  o.e[4] = f2bf(b.x); o.e[5] = f2bf(b.y); o.e[6] = f2bf(b.z); o.e[7] = f2bf(b.w);
  *(short8*)(d + (size_t)i * 8) = o.v;
}

// Wd[e,h,f] -> Wdp[h, e*F+f] (bf16)
__global__ void k_cvt_wd(const float* __restrict__ wd, u16* __restrict__ wdp) {
  int i = blockIdx.x * 256 + threadIdx.x;
  if (i >= (E_NUM * H_DIM * F_DIM) / 8) return;
  int f8 = i & 127;
  int h  = (i >> 7) & (H_DIM - 1);
  int e  = i >> 18;
  const float4* sp = (const float4*)(wd + (size_t)(e * H_DIM + h) * F_DIM + f8 * 8);
  float4 a = sp[0], b = sp[1];
  union { short8 v; u16 ee[8]; } o;
  o.ee[0] = f2bf(a.x); o.ee[1] = f2bf(a.y); o.ee[2] = f2bf(a.z); o.ee[3] = f2bf(a.w);
  o.ee[4] = f2bf(b.x); o.ee[5] = f2bf(b.y); o.ee[6] = f2bf(b.z); o.ee[7] = f2bf(b.w);
  *(short8*)(wdp + (size_t)h * EFD + e * F_DIM + f8 * 8) = o.v;
}

// ================= 8-phase 256x256 BK=64 GEMM core =================
// MODE 0: gate  C=bf16 gpre[(e*T+slot)*F+col], A gathered via list
// MODE 1: up    epilogue: w*silu(gpre)*up -> scatter actS, A gathered
// MODE 2: down  fp32 partial[ks][T,H], split-K
#define STAGE(s_, ab_, h_, t_) do {                                        \
    const u16* s0_ = srcp[ab_][h_][0] + (size_t)(ktile0 + (t_)) * 64;      \
    const u16* s1_ = srcp[ab_][h_][1] + (size_t)(ktile0 + (t_)) * 64;      \
    u16* d_ = lds + (((s_) * 2 + (ab_)) * 16384 + (h_) * 8192 + tid * 8);  \
    gl_lds16(s0_, d_); gl_lds16(s1_, d_ + 4096);                           \
  } while (0)

#define PHASE(p_, STAGE_STMT, WAIT_STMT)                                          \
  {                                                                               \
    afr[0][0] = *(const short8*)(LA + (abase + (2*(p_)) * 1024));                 \
    afr[0][1] = *(const short8*)(LA + ((abase + (2*(p_)) * 1024) ^ 32));          \
    afr[1][0] = *(const short8*)(LA + (abase + (2*(p_)+1) * 1024));               \
    afr[1][1] = *(const short8*)(LA + ((abase + (2*(p_)+1) * 1024) ^ 32));        \
    if ((p_) == 0) {                                                              \
      _Pragma("unroll") for (int n = 0; n < 4; ++n) {                             \
        bfr[n][0] = *(const short8*)(LB + (bbase + n * 1024));                    \
        bfr[n][1] = *(const short8*)(LB + ((bbase + n * 1024) ^ 32));             \
      }                                                                           \
    }                                                                             \
    STAGE_STMT; WAIT_STMT;                                                        \
    __builtin_amdgcn_s_barrier();                                                 \
    __builtin_amdgcn_s_setprio(1);                                                \
    _Pragma("unroll") for (int n = 0; n < 4; ++n) {                               \
      acc[2*(p_)][n]   = __builtin_amdgcn_mfma_f32_16x16x32_bf16(afr[0][0], bfr[n][0], acc[2*(p_)][n],   0,0,0); \
      acc[2*(p_)][n]   = __builtin_amdgcn_mfma_f32_16x16x32_bf16(afr[0][1], bfr[n][1], acc[2*(p_)][n],   0,0,0); \
      acc[2*(p_)+1][n] = __builtin_amdgcn_mfma_f32_16x16x32_bf16(afr[1][0], bfr[n][0], acc[2*(p_)+1][n], 0,0,0); \
      acc[2*(p_)+1][n] = __builtin_amdgcn_mfma_f32_16x16x32_bf16(afr[1][1], bfr[n][1], acc[2*(p_)+1][n], 0,0,0); \
    }                                                                             \
    __builtin_amdgcn_s_setprio(0);                                                \
    __builtin_amdgcn_s_barrier();                                                 \
  }

template<int MODE>
__global__ __launch_bounds__(512, 2)
void k8(const u16* __restrict__ Aglob, const u16* __restrict__ Bglob,
        const int* __restrict__ list, const float* __restrict__ wlist,
        const int* __restrict__ counts, u16* __restrict__ outb,
        const u16* __restrict__ gpre, float* __restrict__ outf)
{
  extern __shared__ u16 lds[];
  const int tid = threadIdx.x;
  const int wid = tid >> 6, lane = tid & 63;
  const int wm = wid >> 2, wn = wid & 3;       // 2 x 4 waves, each 128x64 of C
  const int lr = lane & 15, lk = lane >> 4;

  int e = 0, bm0, bn0, nt, ktile0 = 0;
  size_t Kd;
  if constexpr (MODE < 2) {
    e = blockIdx.z;
    if ((int)blockIdx.y * 256 >= counts[e]) return;
    bm0 = blockIdx.y * 256;
    bn0 = blockIdx.x * 256;
    Kd = H_DIM; nt = H_DIM / 64;
  } else {
    int bid = blockIdx.x;
    int swz = (bid & 7) * 8 + (bid >> 3);      // 64 % 8 == 0: bijective XCD swizzle
    bm0 = (swz >> 3) * 256;
    bn0 = (swz & 7) * 256;
    Kd = EFD; nt = EFD / KSPLIT / 64; ktile0 = blockIdx.y * nt;
  }

  // staging sources: thread handles chunks {tid, tid+512} of each 16KB half.
  // chunk j: row_in_half = j>>3, slot col-chunk = j&7 holds global chunk (j&7)^(row&7)
  const int rl  = tid >> 3;
  const int csw = ((tid & 7) ^ (rl & 7)) * 8;  // swizzled source col (elements)
  const u16* srcp[2][2][2];
#pragma unroll
  for (int h = 0; h < 2; ++h)
#pragma unroll
    for (int c = 0; c < 2; ++c) {
      int arow = bm0 + h * 128 + c * 64 + rl;
      int ar;
      if constexpr (MODE < 2) ar = list[e * T_TOK + arow];
      else ar = arow;
      srcp[0][h][c] = Aglob + (size_t)ar * Kd + csw;
      if constexpr (MODE < 2)
        srcp[1][h][c] = Bglob + (size_t)(e * F_DIM + bn0 + h * 128 + c * 64 + rl) * Kd + csw;
      else
        srcp[1][h][c] = Bglob + (size_t)(bn0 + h * 128 + c * 64 + rl) * Kd + csw;
    }

  f32x4 acc[8][4];
  f32x4 zero4 = {0.f, 0.f, 0.f, 0.f};
#pragma unroll
  for (int m = 0; m < 8; ++m)
#pragma unroll
    for (int n = 0; n < 4; ++n) acc[m][n] = zero4;

  // prologue: tile0 fully + B halves of tile1; retire tile0, keep B(1) in flight
  STAGE(0, 0, 0, 0); STAGE(0, 0, 1, 0); STAGE(0, 1, 0, 0); STAGE(0, 1, 1, 0);
  STAGE(1, 1, 0, 1); STAGE(1, 1, 1, 1);
  asm volatile("s_waitcnt vmcnt(4)" ::: "memory");
  __builtin_amdgcn_s_barrier();

  const int abase = (wm * 128 + lr) * 64 + (lk ^ (lr & 7)) * 8;
  const int bbase = (wn * 64 + lr) * 64 + (lk ^ (lr & 7)) * 8;
  short8 afr[2][2], bfr[4][2];

  for (int t = 0; t < nt; ++t) {
    const int s = t & 1;
    const u16* LA = lds + (size_t)(s * 2) * 16384;
    const u16* LB = lds + (size_t)(s * 2 + 1) * 16384;
    // steady staging: A halves of t+1 (into s^1) at p0/p1; B halves of t+2 (into s) at p2/p3.
    // At p3: in-flight = B01(t+1)[4] + A01(t+1)[4] + B01(t+2)[4]; vmcnt(4) retires tile t+1 exactly.
    PHASE(0, if (t + 1 < nt) STAGE(s ^ 1, 0, 0, t + 1), ((void)0));
    PHASE(1, if (t + 1 < nt) STAGE(s ^ 1, 0, 1, t + 1), ((void)0));
    PHASE(2, if (t + 2 < nt) STAGE(s, 1, 0, t + 2), ((void)0));
    PHASE(3, if (t + 2 < nt) STAGE(s, 1, 1, t + 2),
          if (t + 2 < nt) { asm volatile("s_waitcnt vmcnt(4)" ::: "memory"); }
          else            { asm volatile("s_waitcnt vmcnt(0)" ::: "memory"); });
    __builtin_amdgcn_sched_barrier(0);
  }

  // ---------------- epilogues ----------------
  if constexpr (MODE == 0) {
#pragma unroll
    for (int m = 0; m < 8; ++m)
#pragma unroll
      for (int n = 0; n < 4; ++n)
#pragma unroll
        for (int i = 0; i < 4; ++i) {
          int slot = bm0 + wm * 128 + m * 16 + lk * 4 + i;
          int col  = bn0 + wn * 64 + n * 16 + lr;
          outb[((size_t)e * T_TOK + slot) * F_DIM + col] = f2bf(acc[m][n][i]);
        }
  } else if constexpr (MODE == 1) {
#pragma unroll
    for (int m = 0; m < 8; ++m)
#pragma unroll
      for (int i = 0; i < 4; ++i) {
        int slot = bm0 + wm * 128 + m * 16 + lk * 4 + i;
        float w = wlist[e * T_TOK + slot];
        if (w > 0.f) {
          int tok = list[e * T_TOK + slot];
          const u16* gp = gpre + ((size_t)e * T_TOK + slot) * F_DIM;
          u16* dst = outb + (size_t)tok * EFD + e * F_DIM;
#pragma unroll
          for (int n = 0; n < 4; ++n) {
            int col = bn0 + wn * 64 + n * 16 + lr;
            float g = bf2f(gp[col]);
            float u = acc[m][n][i];
            float act = w * (g / (1.f + expf(-g))) * u;
            dst[col] = f2bf(act);
          }
        }
      }
  } else {
    float* Pk = outf + (size_t)blockIdx.y * T_TOK * H_DIM;
#pragma unroll
    for (int m = 0; m < 8; ++m)
#pragma unroll
      for (int n = 0; n < 4; ++n)
#pragma unroll
        for (int i = 0; i < 4; ++i) {
          int r = bm0 + wm * 128 + m * 16 + lk * 4 + i;
          int c = bn0 + wn * 64 + n * 16 + lr;
          Pk[(size_t)r * H_DIM + c] = acc[m][n][i];
        }
  }
}

// y = sum of KSPLIT partials
__global__ void k_reduce(const float* __restrict__ P, float* __restrict__ y) {
  int i = blockIdx.x * 256 + threadIdx.x;
  const float4* p0 = (const float4*)P;
  const size_t stride = (size_t)T_TOK * H_DIM / 4;
  float4 a = p0[i], b = p0[i + stride], c = p0[i + 2 * stride], d = p0[i + 3 * stride];
  float4 r;
  r.x = (a.x + b.x) + (c.x + d.x);
  r.y = (a.y + b.y) + (c.y + d.y);
  r.z = (a.z + b.z) + (c.z + d.z);
  r.w = (a.w + b.w) + (c.w + d.w);
  ((float4*)y)[i] = r;
}

// ---------------- small GEMM for h1: C = silu(A*B^T + bias) -> bf16 ----------------
__global__ __launch_bounds__(256, 2)
void k_gemm_h1(const u16* __restrict__ A, const u16* __restrict__ B, int Ndim, int Kdim,
               u16* __restrict__ Cb, const float* __restrict__ bias)
{
  __shared__ __align__(16) u16 As[128 * 32];
  __shared__ __align__(16) u16 Bs[64 * 32];
  const int tid = threadIdx.x;
  const int bm0 = blockIdx.y * 128;
  const int bn0 = blockIdx.x * 64;
  const int wid = tid >> 6, lane = tid & 63;
  const int lr = lane & 15, lk = lane >> 4;
  const int srow = tid >> 2, scol = (tid & 3) * 8;

  f32x4 zero4 = {0.f, 0.f, 0.f, 0.f};
  f32x4 acc[2][4];
#pragma unroll
  for (int m = 0; m < 2; ++m)
#pragma unroll
    for (int n = 0; n < 4; ++n) acc[m][n] = zero4;

  const u16* Ag = A + (size_t)(bm0 + srow) * Kdim + scol;
  const u16* Bg = B + (size_t)(bn0 + srow) * Kdim + scol;
  u16* AsP = As + srow * 32 + scol;
  u16* BsP = Bs + srow * 32 + scol;

  for (int k0 = 0; k0 < Kdim; k0 += 32) {
    gl_lds16(Ag + k0, AsP);
    gl_lds16(Ag + k0 + (size_t)64 * Kdim, AsP + 64 * 32);
    gl_lds16(Bg + k0, BsP);
    __syncthreads();
    short8 a[2], b[4];
#pragma unroll
    for (int m = 0; m < 2; ++m)
      a[m] = *(const short8*)(As + (wid * 32 + m * 16 + lr) * 32 + lk * 8);
#pragma unroll
    for (int n = 0; n < 4; ++n)
      b[n] = *(const short8*)(Bs + (n * 16 + lr) * 32 + lk * 8);
#pragma unroll
    for (int m = 0; m < 2; ++m)
#pragma unroll
      for (int n = 0; n < 4; ++n)
        acc[m][n] = __builtin_amdgcn_mfma_f32_16x16x32_bf16(a[m], b[n], acc[m][n], 0, 0, 0);
    __syncthreads();
  }

#pragma unroll
  for (int m = 0; m < 2; ++m)
#pragma unroll
    for (int n = 0; n < 4; ++n)
#pragma unroll
      for (int i = 0; i < 4; ++i) {
        int r = bm0 + wid * 32 + m * 16 + lk * 4 + i;
        int c = bn0 + n * 16 + lr;
        float v = acc[m][n][i] + bias[c];
        v = v / (1.f + expf(-v));
        Cb[(size_t)r * Ndim + c] = f2bf(v);
      }
}

// ---------------- fallback kernels (small-ws path, from R3) ----------------
__global__ __launch_bounds__(256, 2)
void k_down(const u16* __restrict__ A, const u16* __restrict__ B, float* __restrict__ C)
{
  __shared__ __align__(16) u16 As[128 * 32];
  __shared__ __align__(16) u16 Bs[128 * 32];
  const int bid = blockIdx.x;
  const int swz = (bid & 7) * 32 + (bid >> 3);
  const int bm0 = (swz >> 4) * 128;
  const int bn0 = (swz & 15) * 128;
  const int tid = threadIdx.x;
  const int wid = tid >> 6, lane = tid & 63;
  const int wr = (wid >> 1) * 64, wc = (wid & 1) * 64;
  const int lr = lane & 15, lk = lane >> 4;
  const int srow = tid >> 2, scol = (tid & 3) * 8;

  f32x4 zero4 = {0.f, 0.f, 0.f, 0.f};
  f32x4 acc[4][4];
#pragma unroll
  for (int m = 0; m < 4; ++m)
#pragma unroll
    for (int n = 0; n < 4; ++n) acc[m][n] = zero4;

  const u16* Ag = A + (size_t)(bm0 + srow) * EFD + scol;
  const u16* Bg = B + (size_t)(bn0 + srow) * EFD + scol;
  u16* AsP = As + srow * 32 + scol;
  u16* BsP = Bs + srow * 32 + scol;

  for (int k0 = 0; k0 < EFD; k0 += 32) {
    gl_lds16(Ag + k0, AsP);
    gl_lds16(Ag + k0 + (size_t)64 * EFD, AsP + 64 * 32);
    gl_lds16(Bg + k0, BsP);
    gl_lds16(Bg + k0 + (size_t)64 * EFD, BsP + 64 * 32);
    __syncthreads();
    short8 a[4], b[4];
#pragma unroll
    for (int m = 0; m < 4; ++m)
      a[m] = *(const short8*)(As + (wr + m * 16 + lr) * 32 + lk * 8);
#pragma unroll
    for (int n = 0; n < 4; ++n)
      b[n] = *(const short8*)(Bs + (wc + n * 16 + lr) * 32 + lk * 8);
#pragma unroll
    for (int m = 0; m < 4; ++m)
#pragma unroll
      for (int n = 0; n < 4; ++n)
        acc[m][n] = __builtin_amdgcn_mfma_f32_16x16x32_bf16(a[m], b[n], acc[m][n], 0, 0, 0);
    __syncthreads();
  }

#pragma unroll
  for (int m = 0; m < 4; ++m)
#pragma unroll
    for (int n = 0; n < 4; ++n)
#pragma unroll
      for (int i = 0; i < 4; ++i) {
        int r = bm0 + wr + m * 16 + lk * 4 + i;
        int c = bn0 + wc + n * 16 + lr;
        C[(size_t)r * H_DIM + c] = acc[m][n][i];
      }
}

__global__ __launch_bounds__(256, 2)
void k_gu_f32(const u16* __restrict__ Xbf, const float* __restrict__ Wg_, const float* __restrict__ Wu_,
              const int* __restrict__ list, const float* __restrict__ wlist,
              const int* __restrict__ counts, u16* __restrict__ actS)
{
  __shared__ __align__(16) u16 As[128 * 32];
  __shared__ __align__(16) u16 Gs[128 * 32];
  __shared__ __align__(16) u16 Us[128 * 32];
  const int e  = blockIdx.z;
  const int tb = blockIdx.y;
  if (tb * 128 >= counts[e]) return;
  const int f0 = blockIdx.x * 128;
  const int tid = threadIdx.x;
  const int wid = tid >> 6, lane = tid & 63;
  const int wr = (wid >> 1) * 64, wc = (wid & 1) * 64;
  const int lr = lane & 15, lk = lane >> 4;
  const int srow = tid >> 2, scol = (tid & 3) * 8;
  const int lbase = e * T_TOK + tb * 128;

  const int t0i = list[lbase + srow];
  const int t1i = list[lbase + 64 + srow];
  const u16* Ag0 = Xbf + (size_t)t0i * H_DIM + scol;
  const u16* Ag1 = Xbf + (size_t)t1i * H_DIM + scol;
  const size_t wrow = (size_t)(e * F_DIM + f0 + srow) * H_DIM + scol;

  f32x4 zero4 = {0.f, 0.f, 0.f, 0.f};
  f32x4 accg[4][4], accu[4][4];
#pragma unroll
  for (int m = 0; m < 4; ++m)
#pragma unroll
    for (int n = 0; n < 4; ++n) { accg[m][n] = zero4; accu[m][n] = zero4; }

  for (int k0 = 0; k0 < H_DIM; k0 += 32) {
    gl_lds16(Ag0 + k0, As + srow * 32 + scol);
    gl_lds16(Ag1 + k0, As + (64 + srow) * 32 + scol);
#pragma unroll
    for (int half = 0; half < 2; ++half) {
      size_t off = wrow + (size_t)(half * 64) * H_DIM + k0;
      float4 g0 = *(const float4*)(Wg_ + off), g1 = *(const float4*)(Wg_ + off + 4);
      float4 u0 = *(const float4*)(Wu_ + off), u1 = *(const float4*)(Wu_ + off + 4);
      union { short8 v; u16 ee[8]; } og, ou;
      og.ee[0] = f2bf(g0.x); og.ee[1] = f2bf(g0.y); og.ee[2] = f2bf(g0.z); og.ee[3] = f2bf(g0.w);
      og.ee[4] = f2bf(g1.x); og.ee[5] = f2bf(g1.y); og.ee[6] = f2bf(g1.z); og.ee[7] = f2bf(g1.w);
      ou.ee[0] = f2bf(u0.x); ou.ee[1] = f2bf(u0.y); ou.ee[2] = f2bf(u0.z); ou.ee[3] = f2bf(u0.w);
      ou.ee[4] = f2bf(u1.x); ou.ee[5] = f2bf(u1.y); ou.ee[6] = f2bf(u1.z); ou.ee[7] = f2bf(u1.w);
      *(short8*)(Gs + (half * 64 + srow) * 32 + scol) = og.v;
      *(short8*)(Us + (half * 64 + srow) * 32 + scol) = ou.v;
    }
    __syncthreads();
    short8 a[4], bg[4], bu[4];
#pragma unroll
    for (int m = 0; m < 4; ++m)
      a[m] = *(const short8*)(As + (wr + m * 16 + lr) * 32 + lk * 8);
#pragma unroll
    for (int n = 0; n < 4; ++n) {
      bg[n] = *(const short8*)(Gs + (wc + n * 16 + lr) * 32 + lk * 8);
      bu[n] = *(const short8*)(Us + (wc + n * 16 + lr) * 32 + lk * 8);
    }
#pragma unroll
    for (int m = 0; m < 4; ++m)
#pragma unroll
      for (int n = 0; n < 4; ++n) {
        accg[m][n] = __builtin_amdgcn_mfma_f32_16x16x32_bf16(a[m], bg[n], accg[m][n], 0, 0, 0);
        accu[m][n] = __builtin_amdgcn_mfma_f32_16x16x32_bf16(a[m], bu[n], accu[m][n], 0, 0, 0);
      }
    __syncthreads();
  }

#pragma unroll
  for (int m = 0; m < 4; ++m)
#pragma unroll
    for (int i = 0; i < 4; ++i) {
      int slot = tb * 128 + wr + m * 16 + lk * 4 + i;
      float w = wlist[e * T_TOK + slot];
      if (w > 0.f) {
        int t = list[e * T_TOK + slot];
        u16* dst = actS + (size_t)t * EFD + e * F_DIM + f0 + wc;
#pragma unroll
        for (int n = 0; n < 4; ++n) {
          float g = accg[m][n][i], u = accu[m][n][i];
          float act = w * (g / (1.f + expf(-g))) * u;
          dst[n * 16 + lr] = f2bf(act);
        }
      }
    }
}

// ---------------- per-token router ----------------
__global__ void k_router(const float* __restrict__ x, const float* __restrict__ gu,
                         const u16* __restrict__ h1, const float* __restrict__ W2,
                         const float* __restrict__ b2, const float* __restrict__ gw,
                         const float* __restrict__ Umat, const float* __restrict__ alpha_p,
                         float* __restrict__ comb)
{
  __shared__ float xs[H_DIM];
  __shared__ float zbuf[8];
  __shared__ float rl[16];
  __shared__ int zi_s;
  const int t = blockIdx.x, tid = threadIdx.x;

  for (int i = tid; i < H_DIM / 4; i += 256)
    ((float4*)xs)[i] = ((const float4*)(x + (size_t)t * H_DIM))[i];

  int zg = tid >> 5, l32 = tid & 31;
  float zp = 0.f;
  const u16* h1r = h1 + (size_t)t * M_DIM;
  for (int j = l32; j < M_DIM; j += 32)
    zp += bf2f(h1r[j]) * W2[zg * M_DIM + j];
#pragma unroll
  for (int off = 16; off; off >>= 1) zp += __shfl_xor(zp, off);
  if (l32 == 0) zbuf[zg] = zp + b2[zg];
  __syncthreads();
  if (tid == 0) {
    float best = -1e30f; int bi = 0;
#pragma unroll
    for (int z = 0; z < 8; ++z) {
      float u = gu[t * 8 + z];
      float g = -logf(-logf(u + 1e-10f) + 1e-10f);
      float v = zbuf[z] + g;
      if (v > best) { best = v; bi = z; }
    }
    zi_s = bi;
  }
  __syncthreads();
  int eg = tid >> 4, l16 = tid & 15;
  float rp = 0.f;
  const float* gwr = gw + (size_t)eg * H_DIM;
  for (int j = l16; j < H_DIM; j += 16) rp += xs[j] * gwr[j];
#pragma unroll
  for (int off = 8; off; off >>= 1) rp += __shfl_xor(rp, off);
  if (l16 == 0) rl[eg] = rp;
  __syncthreads();
  if (tid == 0) {
    float a = alpha_p[0]; int zi = zi_s;
    float w[16], mx = -1e30f;
#pragma unroll
    for (int ee = 0; ee < 16; ++ee) { w[ee] = rl[ee] + a * Umat[zi * 16 + ee]; mx = fmaxf(mx, w[ee]); }
    float s = 0.f;
#pragma unroll
    for (int ee = 0; ee < 16; ++ee) { w[ee] = expf(w[ee] - mx); s += w[ee]; }
    float inv = 1.f / s;
    unsigned chosen = 0;
#pragma unroll
    for (int k = 0; k < 8; ++k) {
      float bw = -1.f; int bi = 0;
      for (int ee = 0; ee < 16; ++ee)
        if (!((chosen >> ee) & 1u) && w[ee] > bw) { bw = w[ee]; bi = ee; }
      chosen |= 1u << bi;
    }
    for (int ee = 0; ee < 16; ++ee)
      comb[t * 16 + ee] = ((chosen >> ee) & 1u) ? w[ee] * inv : 0.f;
  }
}

// ---------------- deterministic per-expert compaction (pad to 256) ----------------
__global__ void k_compact(const float* __restrict__ comb, int* __restrict__ list,
                          float* __restrict__ wlist, int* __restrict__ counts)
{
  __shared__ int sc[256];
  const int e = blockIdx.x, tid = threadIdx.x;
  int toks[8]; float ws[8]; int cnt = 0;
#pragma unroll
  for (int i = 0; i < 8; ++i) {
    int t = tid * 8 + i;
    float w = comb[t * E_NUM + e];
    if (w > 0.f) { toks[cnt] = t; ws[cnt] = w; ++cnt; }
  }
  sc[tid] = cnt;
  __syncthreads();
  for (int off = 1; off < 256; off <<= 1) {
    int v = (tid >= off) ? sc[tid - off] : 0;
    __syncthreads();
    sc[tid] += v;
    __syncthreads();
  }
  int base = sc[tid] - cnt;
  int total = sc[255];
  int padded = (total + 255) & ~255;
  int* lp = list + e * T_TOK;
  float* wp = wlist + e * T_TOK;
  for (int j = 0; j < cnt; ++j) { lp[base + j] = toks[j]; wp[base + j] = ws[j]; }
  for (int j = total + tid; j < padded; j += 256) { lp[j] = 0; wp[j] = 0.f; }
  if (tid == 0) counts[e] = padded;
}

extern "C" void kernel_launch(void* const* d_in, const int* in_sizes, int n_in,
                              void* d_out, int out_size, void* d_ws, size_t ws_size,
                              hipStream_t stream)
{
  const float* x  = (const float*)d_in[0];
  const float* gu = (const float*)d_in[1];
  const float* W1 = (const float*)d_in[2];
  const float* b1 = (const float*)d_in[3];
  const float* W2 = (const float*)d_in[4];
  const float* b2 = (const float*)d_in[5];
  const float* gw = (const float*)d_in[6];
  const float* Um = (const float*)d_in[7];
  const float* al = (const float*)d_in[8];
  const float* Wg = (const float*)d_in[9];
  const float* Wu = (const float*)d_in[10];
  const float* Wd = (const float*)d_in[11];
  float* y = (float*)d_out;

  size_t off = 0;
  char* base = (char*)d_ws;
  auto take = [&](size_t b) { char* p = base + off; off += (b + 255) & ~(size_t)255; return p; };
  u16*   x_bf   = (u16*)take((size_t)T_TOK * H_DIM * 2);
  u16*   W1_bf  = (u16*)take((size_t)M_DIM * H_DIM * 2);
  u16*   h1_bf  = (u16*)take((size_t)T_TOK * M_DIM * 2);
  u16*   Wdp    = (u16*)take((size_t)H_DIM * EFD * 2);
  u16*   actS   = (u16*)take((size_t)T_TOK * EFD * 2);
  float* comb   = (float*)take((size_t)T_TOK * E_NUM * 4);
  int*   list   = (int*)take((size_t)E_NUM * T_TOK * 4);
  float* wlist  = (float*)take((size_t)E_NUM * T_TOK * 4);
  int*   counts = (int*)take(64 * 4);
  u16*   Wg_bf  = (u16*)take((size_t)E_NUM * F_DIM * H_DIM * 2);  // also: down partials alias here
  u16*   Wu_bf  = (u16*)take((size_t)E_NUM * F_DIM * H_DIM * 2);
  u16*   gpre   = (u16*)take((size_t)E_NUM * T_TOK * F_DIM * 2);
  bool big = (off <= ws_size);
  float* partial = (float*)Wg_bf;   // 67MB, dead after gate-GEMM (KSPLIT*T*H*4 = 64MB)

  hipMemsetAsync(actS, 0, (size_t)T_TOK * EFD * 2, stream);

  k_cvt<<<dim3((T_TOK * H_DIM / 8) / 256), 256, 0, stream>>>(x, x_bf, T_TOK * H_DIM / 8);
  k_cvt<<<dim3((M_DIM * H_DIM / 8) / 256), 256, 0, stream>>>(W1, W1_bf, M_DIM * H_DIM / 8);
  k_cvt_wd<<<dim3((E_NUM * H_DIM * F_DIM / 8) / 256), 256, 0, stream>>>(Wd, Wdp);
  if (big) {
    k_cvt<<<dim3(16384), 256, 0, stream>>>(Wg, Wg_bf, E_NUM * F_DIM * H_DIM / 8);
    k_cvt<<<dim3(16384), 256, 0, stream>>>(Wu, Wu_bf, E_NUM * F_DIM * H_DIM / 8);
  }

  k_gemm_h1<<<dim3(M_DIM / 64, T_TOK / 128), 256, 0, stream>>>(x_bf, W1_bf, M_DIM, H_DIM,
                                                               h1_bf, b1);
  k_router<<<dim3(T_TOK), 256, 0, stream>>>(x, gu, h1_bf, W2, b2, gw, Um, al, comb);
  k_compact<<<dim3(E_NUM), 256, 0, stream>>>(comb, list, wlist, counts);

  if (big) {
    // gate: gpre = Xg @ Wg^T (8-phase, gathered)
    k8<0><<<dim3(F_DIM / 256, 8, E_NUM), 512, 131072, stream>>>(
        x_bf, Wg_bf, list, wlist, counts, gpre, nullptr, nullptr);
    // up + fused combine/scatter into actS
    k8<1><<<dim3(F_DIM / 256, 8, E_NUM), 512, 131072, stream>>>(
        x_bf, Wu_bf, list, wlist, counts, actS, gpre, nullptr);
    // down, split-K (partials alias Wg_bf region, dead now)
    k8<2><<<dim3(64, KSPLIT), 512, 131072, stream>>>(
        actS, Wdp, nullptr, nullptr, nullptr, nullptr, nullptr, partial);
    k_reduce<<<dim3((T_TOK * H_DIM / 4) / 256), 256, 0, stream>>>(partial, y);
  } else {
    k_gu_f32<<<dim3(F_DIM / 128, 16, E_NUM), 256, 0, stream>>>(x_bf, Wg, Wu,
                                                               list, wlist, counts, actS);
    k_down<<<dim3(256), 256, 0, stream>>>(actS, Wdp, y);
  }
}

// Round 6
// 493.591 us; speedup vs baseline: 1.7061x; 1.2537x over previous
//
#include <hip/hip_runtime.h>
#include <math.h>

typedef unsigned short u16;
typedef __attribute__((ext_vector_type(8))) short short8;
typedef __attribute__((ext_vector_type(4))) float f32x4;

#define T_TOK 2048
#define H_DIM 2048
#define E_NUM 16
#define F_DIM 1024
#define EFD   16384
#define M_DIM 512
#define SLOTMAX 2048

__device__ __forceinline__ u16 f2bf(float x) {
  union { float f; unsigned u; } c; c.f = x;
  unsigned r = c.u + 0x7FFFu + ((c.u >> 16) & 1u);   // RNE
  return (u16)(r >> 16);
}
__device__ __forceinline__ float bf2f(u16 h) {
  union { unsigned u; float f; } c; c.u = ((unsigned)h) << 16;
  return c.f;
}
__device__ __forceinline__ void gl_lds16(const void* g, void* l) {
  __builtin_amdgcn_global_load_lds((const __attribute__((address_space(1))) void*)g,
                                   (__attribute__((address_space(3))) void*)l, 16, 0, 0);
}

// ---------------- conversion kernels ----------------
__global__ void k_cvt(const float* __restrict__ s, u16* __restrict__ d, int n8) {
  int i = blockIdx.x * 256 + threadIdx.x;
  if (i >= n8) return;
  const float4* sp = (const float4*)(s + (size_t)i * 8);
  float4 a = sp[0], b = sp[1];
  union { short8 v; u16 e[8]; } o;
  o.e[0] = f2bf(a.x); o.e[1] = f2bf(a.y); o.e[2] = f2bf(a.z); o.e[3] = f2bf(a.w);
  o.e[4] = f2bf(b.x); o.e[5] = f2bf(b.y); o.e[6] = f2bf(b.z); o.e[7] = f2bf(b.w);
  *(short8*)(d + (size_t)i * 8) = o.v;
}

// Wd[e,h,f] -> Wdp[h, e*F+f] (bf16)  [fallback path only]
__global__ void k_cvt_wd(const float* __restrict__ wd, u16* __restrict__ wdp) {
  int i = blockIdx.x * 256 + threadIdx.x;
  if (i >= (E_NUM * H_DIM * F_DIM) / 8) return;
  int f8 = i & 127;
  int h  = (i >> 7) & (H_DIM - 1);
  int e  = i >> 18;
  const float4* sp = (const float4*)(wd + (size_t)(e * H_DIM + h) * F_DIM + f8 * 8);
  float4 a = sp[0], b = sp[1];
  union { short8 v; u16 ee[8]; } o;
  o.ee[0] = f2bf(a.x); o.ee[1] = f2bf(a.y); o.ee[2] = f2bf(a.z); o.ee[3] = f2bf(a.w);
  o.ee[4] = f2bf(b.x); o.ee[5] = f2bf(b.y); o.ee[6] = f2bf(b.z); o.ee[7] = f2bf(b.w);
  *(short8*)(wdp + (size_t)h * EFD + e * F_DIM + f8 * 8) = o.v;
}

// ============ shared 8-phase machinery (identical schedule to R4, verified) ============
#define STAGE8(s_, ab_, h_, t_) do {                                       \
    const u16* s0_ = srcp[ab_][h_][0] + (size_t)(t_) * 64;                 \
    const u16* s1_ = srcp[ab_][h_][1] + (size_t)(t_) * 64;                 \
    u16* d_ = lds + (((s_) * 2 + (ab_)) * 16384 + (h_) * 8192 + tid * 8);  \
    gl_lds16(s0_, d_); gl_lds16(s1_, d_ + 4096);                           \
  } while (0)

// ---------------- merged gate+up: actC[e][slot][f] = w*silu(g)*u ----------------
// block: 512 thr, C-tile 256 slots x 128 f (both G and U). B-halves: h=0 Wg, h=1 Wu.
#define PHASE_GU(p_, STAGE_STMT, WAIT_STMT)                                       \
  {                                                                               \
    afr[0][0] = *(const short8*)(LA + (abase + (2*(p_)) * 1024));                 \
    afr[0][1] = *(const short8*)(LA + ((abase + (2*(p_)) * 1024) ^ 32));          \
    afr[1][0] = *(const short8*)(LA + (abase + (2*(p_)+1) * 1024));               \
    afr[1][1] = *(const short8*)(LA + ((abase + (2*(p_)+1) * 1024) ^ 32));        \
    if ((p_) == 0) {                                                              \
      _Pragma("unroll") for (int n = 0; n < 2; ++n) {                             \
        gfr[n][0] = *(const short8*)(LB + (bbase + n * 1024));                    \
        gfr[n][1] = *(const short8*)(LB + ((bbase + n * 1024) ^ 32));             \
        ufr[n][0] = *(const short8*)(LB + (8192 + bbase + n * 1024));             \
        ufr[n][1] = *(const short8*)(LB + ((8192 + bbase + n * 1024) ^ 32));      \
      }                                                                           \
    }                                                                             \
    STAGE_STMT; WAIT_STMT;                                                        \
    __builtin_amdgcn_s_barrier();                                                 \
    __builtin_amdgcn_s_setprio(1);                                                \
    _Pragma("unroll") for (int n = 0; n < 2; ++n)                                 \
      _Pragma("unroll") for (int kk = 0; kk < 2; ++kk) {                          \
        accg[2*(p_)][n]   = __builtin_amdgcn_mfma_f32_16x16x32_bf16(afr[0][kk], gfr[n][kk], accg[2*(p_)][n],   0,0,0); \
        accg[2*(p_)+1][n] = __builtin_amdgcn_mfma_f32_16x16x32_bf16(afr[1][kk], gfr[n][kk], accg[2*(p_)+1][n], 0,0,0); \
        accu[2*(p_)][n]   = __builtin_amdgcn_mfma_f32_16x16x32_bf16(afr[0][kk], ufr[n][kk], accu[2*(p_)][n],   0,0,0); \
        accu[2*(p_)+1][n] = __builtin_amdgcn_mfma_f32_16x16x32_bf16(afr[1][kk], ufr[n][kk], accu[2*(p_)+1][n], 0,0,0); \
      }                                                                           \
    __builtin_amdgcn_s_setprio(0);                                                \
    __builtin_amdgcn_s_barrier();                                                 \
  }

__global__ __launch_bounds__(512, 2)
void k8gu(const u16* __restrict__ Xbf, const u16* __restrict__ Wg, const u16* __restrict__ Wu,
          const int* __restrict__ list, const float* __restrict__ wlist,
          const int* __restrict__ counts, u16* __restrict__ actC)
{
  extern __shared__ u16 lds[];
  const int tid = threadIdx.x;
  const int wid = tid >> 6, lane = tid & 63;
  const int wm = wid >> 2, wn = wid & 3;       // wave tile: 128 slots x 32 cols
  const int lr = lane & 15, lk = lane >> 4;
  const int e = blockIdx.z;
  if ((int)blockIdx.y * 256 >= counts[e]) return;
  const int bm0 = blockIdx.y * 256;
  const int bn0 = blockIdx.x * 128;
  const int nt = H_DIM / 64;

  const int rl  = tid >> 3;
  const int csw = ((tid & 7) ^ (rl & 7)) * 8;
  const u16* srcp[2][2][2];
#pragma unroll
  for (int h = 0; h < 2; ++h)
#pragma unroll
    for (int c = 0; c < 2; ++c) {
      int ar = list[e * T_TOK + bm0 + h * 128 + c * 64 + rl];
      srcp[0][h][c] = Xbf + (size_t)ar * H_DIM + csw;
      size_t brow = (size_t)(e * F_DIM + bn0 + c * 64 + rl);
      srcp[1][h][c] = (h == 0 ? Wg : Wu) + brow * H_DIM + csw;
    }

  f32x4 accg[8][2], accu[8][2];
  f32x4 zero4 = {0.f, 0.f, 0.f, 0.f};
#pragma unroll
  for (int m = 0; m < 8; ++m)
#pragma unroll
    for (int n = 0; n < 2; ++n) { accg[m][n] = zero4; accu[m][n] = zero4; }

  STAGE8(0, 0, 0, 0); STAGE8(0, 0, 1, 0); STAGE8(0, 1, 0, 0); STAGE8(0, 1, 1, 0);
  STAGE8(1, 1, 0, 1); STAGE8(1, 1, 1, 1);
  asm volatile("s_waitcnt vmcnt(4)" ::: "memory");
  __builtin_amdgcn_s_barrier();

  const int abase = (wm * 128 + lr) * 64 + (lk ^ (lr & 7)) * 8;
  const int bbase = (wn * 32 + lr) * 64 + (lk ^ (lr & 7)) * 8;
  short8 afr[2][2], gfr[2][2], ufr[2][2];

  for (int t = 0; t < nt; ++t) {
    const int s = t & 1;
    const u16* LA = lds + (size_t)(s * 2) * 16384;
    const u16* LB = lds + (size_t)(s * 2 + 1) * 16384;
    PHASE_GU(0, if (t + 1 < nt) STAGE8(s ^ 1, 0, 0, t + 1), ((void)0));
    PHASE_GU(1, if (t + 1 < nt) STAGE8(s ^ 1, 0, 1, t + 1), ((void)0));
    PHASE_GU(2, if (t + 2 < nt) STAGE8(s, 1, 0, t + 2), ((void)0));
    PHASE_GU(3, if (t + 2 < nt) STAGE8(s, 1, 1, t + 2),
             if (t + 2 < nt) { asm volatile("s_waitcnt vmcnt(4)" ::: "memory"); }
             else            { asm volatile("s_waitcnt vmcnt(0)" ::: "memory"); });
    __builtin_amdgcn_sched_barrier(0);
  }

#pragma unroll
  for (int m = 0; m < 8; ++m)
#pragma unroll
    for (int i = 0; i < 4; ++i) {
      int slot = bm0 + wm * 128 + m * 16 + lk * 4 + i;
      float w = wlist[e * T_TOK + slot];
#pragma unroll
      for (int n = 0; n < 2; ++n) {
        int col = bn0 + wn * 32 + n * 16 + lr;
        float g = accg[m][n][i], u = accu[m][n][i];
        float act = w * (g / (1.f + expf(-g))) * u;
        actC[((size_t)e * SLOTMAX + slot) * F_DIM + col] = f2bf(act);
      }
    }
}

// ---------------- per-expert down: outE[e][slot][h] = actC_e @ Wd_e^T (bf16) ------------
#define PHASE_D(p_, STAGE_STMT, WAIT_STMT)                                        \
  {                                                                               \
    afr[0][0] = *(const short8*)(LA + (abase + (2*(p_)) * 1024));                 \
    afr[0][1] = *(const short8*)(LA + ((abase + (2*(p_)) * 1024) ^ 32));          \
    afr[1][0] = *(const short8*)(LA + (abase + (2*(p_)+1) * 1024));               \
    afr[1][1] = *(const short8*)(LA + ((abase + (2*(p_)+1) * 1024) ^ 32));        \
    if ((p_) == 0) {                                                              \
      _Pragma("unroll") for (int n = 0; n < 4; ++n) {                             \
        bfr[n][0] = *(const short8*)(LB + (bbase + n * 1024));                    \
        bfr[n][1] = *(const short8*)(LB + ((bbase + n * 1024) ^ 32));             \
      }                                                                           \
    }                                                                             \
    STAGE_STMT; WAIT_STMT;                                                        \
    __builtin_amdgcn_s_barrier();                                                 \
    __builtin_amdgcn_s_setprio(1);                                                \
    _Pragma("unroll") for (int n = 0; n < 4; ++n) {                               \
      acc[2*(p_)][n]   = __builtin_amdgcn_mfma_f32_16x16x32_bf16(afr[0][0], bfr[n][0], acc[2*(p_)][n],   0,0,0); \
      acc[2*(p_)][n]   = __builtin_amdgcn_mfma_f32_16x16x32_bf16(afr[0][1], bfr[n][1], acc[2*(p_)][n],   0,0,0); \
      acc[2*(p_)+1][n] = __builtin_amdgcn_mfma_f32_16x16x32_bf16(afr[1][0], bfr[n][0], acc[2*(p_)+1][n], 0,0,0); \
      acc[2*(p_)+1][n] = __builtin_amdgcn_mfma_f32_16x16x32_bf16(afr[1][1], bfr[n][1], acc[2*(p_)+1][n], 0,0,0); \
    }                                                                             \
    __builtin_amdgcn_s_setprio(0);                                                \
    __builtin_amdgcn_s_barrier();                                                 \
  }

__global__ __launch_bounds__(512, 2)
void k8d(const u16* __restrict__ actC, const u16* __restrict__ Wd,
         const int* __restrict__ counts, u16* __restrict__ outE)
{
  extern __shared__ u16 lds[];
  const int tid = threadIdx.x;
  const int wid = tid >> 6, lane = tid & 63;
  const int wm = wid >> 2, wn = wid & 3;       // wave tile: 128 slots x 64 h
  const int lr = lane & 15, lk = lane >> 4;
  const int e = blockIdx.z;
  if ((int)blockIdx.y * 256 >= counts[e]) return;
  const int bm0 = blockIdx.y * 256;
  const int bn0 = blockIdx.x * 256;
  const int nt = F_DIM / 64;

  const int rl  = tid >> 3;
  const int csw = ((tid & 7) ^ (rl & 7)) * 8;
  const u16* srcp[2][2][2];
#pragma unroll
  for (int h = 0; h < 2; ++h)
#pragma unroll
    for (int c = 0; c < 2; ++c) {
      srcp[0][h][c] = actC + ((size_t)e * SLOTMAX + bm0 + h * 128 + c * 64 + rl) * F_DIM + csw;
      srcp[1][h][c] = Wd + (size_t)e * H_DIM * F_DIM
                    + (size_t)(bn0 + h * 128 + c * 64 + rl) * F_DIM + csw;
    }

  f32x4 acc[8][4];
  f32x4 zero4 = {0.f, 0.f, 0.f, 0.f};
#pragma unroll
  for (int m = 0; m < 8; ++m)
#pragma unroll
    for (int n = 0; n < 4; ++n) acc[m][n] = zero4;

  STAGE8(0, 0, 0, 0); STAGE8(0, 0, 1, 0); STAGE8(0, 1, 0, 0); STAGE8(0, 1, 1, 0);
  STAGE8(1, 1, 0, 1); STAGE8(1, 1, 1, 1);
  asm volatile("s_waitcnt vmcnt(4)" ::: "memory");
  __builtin_amdgcn_s_barrier();

  const int abase = (wm * 128 + lr) * 64 + (lk ^ (lr & 7)) * 8;
  const int bbase = (wn * 64 + lr) * 64 + (lk ^ (lr & 7)) * 8;
  short8 afr[2][2], bfr[4][2];

  for (int t = 0; t < nt; ++t) {
    const int s = t & 1;
    const u16* LA = lds + (size_t)(s * 2) * 16384;
    const u16* LB = lds + (size_t)(s * 2 + 1) * 16384;
    PHASE_D(0, if (t + 1 < nt) STAGE8(s ^ 1, 0, 0, t + 1), ((void)0));
    PHASE_D(1, if (t + 1 < nt) STAGE8(s ^ 1, 0, 1, t + 1), ((void)0));
    PHASE_D(2, if (t + 2 < nt) STAGE8(s, 1, 0, t + 2), ((void)0));
    PHASE_D(3, if (t + 2 < nt) STAGE8(s, 1, 1, t + 2),
            if (t + 2 < nt) { asm volatile("s_waitcnt vmcnt(4)" ::: "memory"); }
            else            { asm volatile("s_waitcnt vmcnt(0)" ::: "memory"); });
    __builtin_amdgcn_sched_barrier(0);
  }

#pragma unroll
  for (int m = 0; m < 8; ++m)
#pragma unroll
    for (int n = 0; n < 4; ++n)
#pragma unroll
      for (int i = 0; i < 4; ++i) {
        int slot = bm0 + wm * 128 + m * 16 + lk * 4 + i;
        int col  = bn0 + wn * 64 + n * 16 + lr;
        outE[((size_t)e * SLOTMAX + slot) * H_DIM + col] = f2bf(acc[m][n][i]);
      }
}

// ---------------- tokmap: inverse index (t, rank) -> e*SLOTMAX+slot ----------------
__global__ void k_tokmap(const int* __restrict__ list, const float* __restrict__ wlist,
                         const int* __restrict__ counts, const unsigned* __restrict__ emask,
                         int* __restrict__ tokmap)
{
  int e = blockIdx.x;
  int cnt = counts[e];
  for (int slot = threadIdx.x; slot < cnt; slot += 256) {
    float w = wlist[e * T_TOK + slot];
    if (w <= 0.f) continue;
    int t = list[e * T_TOK + slot];
    int r = __popc(emask[t] & ((1u << e) - 1u));
    tokmap[t * 8 + r] = e * SLOTMAX + slot;
  }
}

// ---------------- gather-reduce: y[t,h] = sum_{r<8} outE[tokmap[t][r]][h] ----------------
__global__ void k_gather(const u16* __restrict__ outE, const int* __restrict__ tokmap,
                         float* __restrict__ y)
{
  __shared__ int tm[8];
  const int t = blockIdx.x, tid = threadIdx.x;
  if (tid < 8) tm[tid] = tokmap[t * 8 + tid];
  __syncthreads();
  float s[8] = {0.f, 0.f, 0.f, 0.f, 0.f, 0.f, 0.f, 0.f};
#pragma unroll
  for (int r = 0; r < 8; ++r) {
    union { short8 v; u16 e[8]; } row;
    row.v = *(const short8*)(outE + (size_t)tm[r] * H_DIM + tid * 8);
#pragma unroll
    for (int j = 0; j < 8; ++j) s[j] += bf2f(row.e[j]);
  }
  float* dst = y + (size_t)t * H_DIM + tid * 8;
#pragma unroll
  for (int j = 0; j < 8; ++j) dst[j] = s[j];
}

// ---------------- small GEMM for h1: C = silu(A*B^T + bias) -> bf16 ----------------
__global__ __launch_bounds__(256, 2)
void k_gemm_h1(const u16* __restrict__ A, const u16* __restrict__ B, int Ndim, int Kdim,
               u16* __restrict__ Cb, const float* __restrict__ bias)
{
  __shared__ __align__(16) u16 As[128 * 32];
  __shared__ __align__(16) u16 Bs[64 * 32];
  const int tid = threadIdx.x;
  const int bm0 = blockIdx.y * 128;
  const int bn0 = blockIdx.x * 64;
  const int wid = tid >> 6, lane = tid & 63;
  const int lr = lane & 15, lk = lane >> 4;
  const int srow = tid >> 2, scol = (tid & 3) * 8;

  f32x4 zero4 = {0.f, 0.f, 0.f, 0.f};
  f32x4 acc[2][4];
#pragma unroll
  for (int m = 0; m < 2; ++m)
#pragma unroll
    for (int n = 0; n < 4; ++n) acc[m][n] = zero4;

  const u16* Ag = A + (size_t)(bm0 + srow) * Kdim + scol;
  const u16* Bg = B + (size_t)(bn0 + srow) * Kdim + scol;
  u16* AsP = As + srow * 32 + scol;
  u16* BsP = Bs + srow * 32 + scol;

  for (int k0 = 0; k0 < Kdim; k0 += 32) {
    gl_lds16(Ag + k0, AsP);
    gl_lds16(Ag + k0 + (size_t)64 * Kdim, AsP + 64 * 32);
    gl_lds16(Bg + k0, BsP);
    __syncthreads();
    short8 a[2], b[4];
#pragma unroll
    for (int m = 0; m < 2; ++m)
      a[m] = *(const short8*)(As + (wid * 32 + m * 16 + lr) * 32 + lk * 8);
#pragma unroll
    for (int n = 0; n < 4; ++n)
      b[n] = *(const short8*)(Bs + (n * 16 + lr) * 32 + lk * 8);
#pragma unroll
    for (int m = 0; m < 2; ++m)
#pragma unroll
      for (int n = 0; n < 4; ++n)
        acc[m][n] = __builtin_amdgcn_mfma_f32_16x16x32_bf16(a[m], b[n], acc[m][n], 0, 0, 0);
    __syncthreads();
  }

#pragma unroll
  for (int m = 0; m < 2; ++m)
#pragma unroll
    for (int n = 0; n < 4; ++n)
#pragma unroll
      for (int i = 0; i < 4; ++i) {
        int r = bm0 + wid * 32 + m * 16 + lk * 4 + i;
        int c = bn0 + n * 16 + lr;
        float v = acc[m][n][i] + bias[c];
        v = v / (1.f + expf(-v));
        Cb[(size_t)r * Ndim + c] = f2bf(v);
      }
}

// ---------------- fallback kernels (small-ws path) ----------------
__global__ __launch_bounds__(256, 2)
void k_down(const u16* __restrict__ A, const u16* __restrict__ B, float* __restrict__ C)
{
  __shared__ __align__(16) u16 As[128 * 32];
  __shared__ __align__(16) u16 Bs[128 * 32];
  const int bid = blockIdx.x;
  const int swz = (bid & 7) * 32 + (bid >> 3);
  const int bm0 = (swz >> 4) * 128;
  const int bn0 = (swz & 15) * 128;
  const int tid = threadIdx.x;
  const int wid = tid >> 6, lane = tid & 63;
  const int wr = (wid >> 1) * 64, wc = (wid & 1) * 64;
  const int lr = lane & 15, lk = lane >> 4;
  const int srow = tid >> 2, scol = (tid & 3) * 8;

  f32x4 zero4 = {0.f, 0.f, 0.f, 0.f};
  f32x4 acc[4][4];
#pragma unroll
  for (int m = 0; m < 4; ++m)
#pragma unroll
    for (int n = 0; n < 4; ++n) acc[m][n] = zero4;

  const u16* Ag = A + (size_t)(bm0 + srow) * EFD + scol;
  const u16* Bg = B + (size_t)(bn0 + srow) * EFD + scol;
  u16* AsP = As + srow * 32 + scol;
  u16* BsP = Bs + srow * 32 + scol;

  for (int k0 = 0; k0 < EFD; k0 += 32) {
    gl_lds16(Ag + k0, AsP);
    gl_lds16(Ag + k0 + (size_t)64 * EFD, AsP + 64 * 32);
    gl_lds16(Bg + k0, BsP);
    gl_lds16(Bg + k0 + (size_t)64 * EFD, BsP + 64 * 32);
    __syncthreads();
    short8 a[4], b[4];
#pragma unroll
    for (int m = 0; m < 4; ++m)
      a[m] = *(const short8*)(As + (wr + m * 16 + lr) * 32 + lk * 8);
#pragma unroll
    for (int n = 0; n < 4; ++n)
      b[n] = *(const short8*)(Bs + (wc + n * 16 + lr) * 32 + lk * 8);
#pragma unroll
    for (int m = 0; m < 4; ++m)
#pragma unroll
      for (int n = 0; n < 4; ++n)
        acc[m][n] = __builtin_amdgcn_mfma_f32_16x16x32_bf16(a[m], b[n], acc[m][n], 0, 0, 0);
    __syncthreads();
  }

#pragma unroll
  for (int m = 0; m < 4; ++m)
#pragma unroll
    for (int n = 0; n < 4; ++n)
#pragma unroll
      for (int i = 0; i < 4; ++i) {
        int r = bm0 + wr + m * 16 + lk * 4 + i;
        int c = bn0 + wc + n * 16 + lr;
        C[(size_t)r * H_DIM + c] = acc[m][n][i];
      }
}

__global__ __launch_bounds__(256, 2)
void k_gu_f32(const u16* __restrict__ Xbf, const float* __restrict__ Wg_, const float* __restrict__ Wu_,
              const int* __restrict__ list, const float* __restrict__ wlist,
              const int* __restrict__ counts, u16* __restrict__ actS)
{
  __shared__ __align__(16) u16 As[128 * 32];
  __shared__ __align__(16) u16 Gs[128 * 32];
  __shared__ __align__(16) u16 Us[128 * 32];
  const int e  = blockIdx.z;
  const int tb = blockIdx.y;
  if (tb * 128 >= counts[e]) return;
  const int f0 = blockIdx.x * 128;
  const int tid = threadIdx.x;
  const int wid = tid >> 6, lane = tid & 63;
  const int wr = (wid >> 1) * 64, wc = (wid & 1) * 64;
  const int lr = lane & 15, lk = lane >> 4;
  const int srow = tid >> 2, scol = (tid & 3) * 8;
  const int lbase = e * T_TOK + tb * 128;

  const int t0i = list[lbase + srow];
  const int t1i = list[lbase + 64 + srow];
  const u16* Ag0 = Xbf + (size_t)t0i * H_DIM + scol;
  const u16* Ag1 = Xbf + (size_t)t1i * H_DIM + scol;
  const size_t wrow = (size_t)(e * F_DIM + f0 + srow) * H_DIM + scol;

  f32x4 zero4 = {0.f, 0.f, 0.f, 0.f};
  f32x4 accg[4][4], accu[4][4];
#pragma unroll
  for (int m = 0; m < 4; ++m)
#pragma unroll
    for (int n = 0; n < 4; ++n) { accg[m][n] = zero4; accu[m][n] = zero4; }

  for (int k0 = 0; k0 < H_DIM; k0 += 32) {
    gl_lds16(Ag0 + k0, As + srow * 32 + scol);
    gl_lds16(Ag1 + k0, As + (64 + srow) * 32 + scol);
#pragma unroll
    for (int half = 0; half < 2; ++half) {
      size_t off = wrow + (size_t)(half * 64) * H_DIM + k0;
      float4 g0 = *(const float4*)(Wg_ + off), g1 = *(const float4*)(Wg_ + off + 4);
      float4 u0 = *(const float4*)(Wu_ + off), u1 = *(const float4*)(Wu_ + off + 4);
      union { short8 v; u16 ee[8]; } og, ou;
      og.ee[0] = f2bf(g0.x); og.ee[1] = f2bf(g0.y); og.ee[2] = f2bf(g0.z); og.ee[3] = f2bf(g0.w);
      og.ee[4] = f2bf(g1.x); og.ee[5] = f2bf(g1.y); og.ee[6] = f2bf(g1.z); og.ee[7] = f2bf(g1.w);
      ou.ee[0] = f2bf(u0.x); ou.ee[1] = f2bf(u0.y); ou.ee[2] = f2bf(u0.z); ou.ee[3] = f2bf(u0.w);
      ou.ee[4] = f2bf(u1.x); ou.ee[5] = f2bf(u1.y); ou.ee[6] = f2bf(u1.z); ou.ee[7] = f2bf(u1.w);
      *(short8*)(Gs + (half * 64 + srow) * 32 + scol) = og.v;
      *(short8*)(Us + (half * 64 + srow) * 32 + scol) = ou.v;
    }
    __syncthreads();
    short8 a[4], bg[4], bu[4];
#pragma unroll
    for (int m = 0; m < 4; ++m)
      a[m] = *(const short8*)(As + (wr + m * 16 + lr) * 32 + lk * 8);
#pragma unroll
    for (int n = 0; n < 4; ++n) {
      bg[n] = *(const short8*)(Gs + (wc + n * 16 + lr) * 32 + lk * 8);
      bu[n] = *(const short8*)(Us + (wc + n * 16 + lr) * 32 + lk * 8);
    }
#pragma unroll
    for (int m = 0; m < 4; ++m)
#pragma unroll
      for (int n = 0; n < 4; ++n) {
        accg[m][n] = __builtin_amdgcn_mfma_f32_16x16x32_bf16(a[m], bg[n], accg[m][n], 0, 0, 0);
        accu[m][n] = __builtin_amdgcn_mfma_f32_16x16x32_bf16(a[m], bu[n], accu[m][n], 0, 0, 0);
      }
    __syncthreads();
  }

#pragma unroll
  for (int m = 0; m < 4; ++m)
#pragma unroll
    for (int i = 0; i < 4; ++i) {
      int slot = tb * 128 + wr + m * 16 + lk * 4 + i;
      float w = wlist[e * T_TOK + slot];
      if (w > 0.f) {
        int t = list[e * T_TOK + slot];
        u16* dst = actS + (size_t)t * EFD + e * F_DIM + f0 + wc;
#pragma unroll
        for (int n = 0; n < 4; ++n) {
          float g = accg[m][n][i], u = accu[m][n][i];
          float act = w * (g / (1.f + expf(-g))) * u;
          dst[n * 16 + lr] = f2bf(act);
        }
      }
    }
}

// ---------------- per-token router (+ expert bitmask out) ----------------
__global__ void k_router(const float* __restrict__ x, const float* __restrict__ gu,
                         const u16* __restrict__ h1, const float* __restrict__ W2,
                         const float* __restrict__ b2, const float* __restrict__ gw,
                         const float* __restrict__ Umat, const float* __restrict__ alpha_p,
                         float* __restrict__ comb, unsigned* __restrict__ emask)
{
  __shared__ float xs[H_DIM];
  __shared__ float zbuf[8];
  __shared__ float rl[16];
  __shared__ int zi_s;
  const int t = blockIdx.x, tid = threadIdx.x;

  for (int i = tid; i < H_DIM / 4; i += 256)
    ((float4*)xs)[i] = ((const float4*)(x + (size_t)t * H_DIM))[i];

  int zg = tid >> 5, l32 = tid & 31;
  float zp = 0.f;
  const u16* h1r = h1 + (size_t)t * M_DIM;
  for (int j = l32; j < M_DIM; j += 32)
    zp += bf2f(h1r[j]) * W2[zg * M_DIM + j];
#pragma unroll
  for (int off = 16; off; off >>= 1) zp += __shfl_xor(zp, off);
  if (l32 == 0) zbuf[zg] = zp + b2[zg];
  __syncthreads();
  if (tid == 0) {
    float best = -1e30f; int bi = 0;
#pragma unroll
    for (int z = 0; z < 8; ++z) {
      float u = gu[t * 8 + z];
      float g = -logf(-logf(u + 1e-10f) + 1e-10f);
      float v = zbuf[z] + g;
      if (v > best) { best = v; bi = z; }
    }
    zi_s = bi;
  }
  __syncthreads();
  int eg = tid >> 4, l16 = tid & 15;
  float rp = 0.f;
  const float* gwr = gw + (size_t)eg * H_DIM;
  for (int j = l16; j < H_DIM; j += 16) rp += xs[j] * gwr[j];
#pragma unroll
  for (int off = 8; off; off >>= 1) rp += __shfl_xor(rp, off);
  if (l16 == 0) rl[eg] = rp;
  __syncthreads();
  if (tid == 0) {
    float a = alpha_p[0]; int zi = zi_s;
    float w[16], mx = -1e30f;
#pragma unroll
    for (int ee = 0; ee < 16; ++ee) { w[ee] = rl[ee] + a * Umat[zi * 16 + ee]; mx = fmaxf(mx, w[ee]); }
    float s = 0.f;
#pragma unroll
    for (int ee = 0; ee < 16; ++ee) { w[ee] = expf(w[ee] - mx); s += w[ee]; }
    float inv = 1.f / s;
    unsigned chosen = 0;
#pragma unroll
    for (int k = 0; k < 8; ++k) {
      float bw = -1.f; int bi = 0;
      for (int ee = 0; ee < 16; ++ee)
        if (!((chosen >> ee) & 1u) && w[ee] > bw) { bw = w[ee]; bi = ee; }
      chosen |= 1u << bi;
    }
    for (int ee = 0; ee < 16; ++ee)
      comb[t * 16 + ee] = ((chosen >> ee) & 1u) ? w[ee] * inv : 0.f;
    emask[t] = chosen;
  }
}

// ---------------- deterministic per-expert compaction (pad to 256) ----------------
__global__ void k_compact(const float* __restrict__ comb, int* __restrict__ list,
                          float* __restrict__ wlist, int* __restrict__ counts)
{
  __shared__ int sc[256];
  const int e = blockIdx.x, tid = threadIdx.x;
  int toks[8]; float ws[8]; int cnt = 0;
#pragma unroll
  for (int i = 0; i < 8; ++i) {
    int t = tid * 8 + i;
    float w = comb[t * E_NUM + e];
    if (w > 0.f) { toks[cnt] = t; ws[cnt] = w; ++cnt; }
  }
  sc[tid] = cnt;
  __syncthreads();
  for (int off = 1; off < 256; off <<= 1) {
    int v = (tid >= off) ? sc[tid - off] : 0;
    __syncthreads();
    sc[tid] += v;
    __syncthreads();
  }
  int base = sc[tid] - cnt;
  int total = sc[255];
  int padded = (total + 255) & ~255;
  int* lp = list + e * T_TOK;
  float* wp = wlist + e * T_TOK;
  for (int j = 0; j < cnt; ++j) { lp[base + j] = toks[j]; wp[base + j] = ws[j]; }
  for (int j = total + tid; j < padded; j += 256) { lp[j] = 0; wp[j] = 0.f; }
  if (tid == 0) counts[e] = padded;
}

extern "C" void kernel_launch(void* const* d_in, const int* in_sizes, int n_in,
                              void* d_out, int out_size, void* d_ws, size_t ws_size,
                              hipStream_t stream)
{
  const float* x  = (const float*)d_in[0];
  const float* gu = (const float*)d_in[1];
  const float* W1 = (const float*)d_in[2];
  const float* b1 = (const float*)d_in[3];
  const float* W2 = (const float*)d_in[4];
  const float* b2 = (const float*)d_in[5];
  const float* gw = (const float*)d_in[6];
  const float* Um = (const float*)d_in[7];
  const float* al = (const float*)d_in[8];
  const float* Wg = (const float*)d_in[9];
  const float* Wu = (const float*)d_in[10];
  const float* Wd = (const float*)d_in[11];
  float* y = (float*)d_out;

  size_t off = 0;
  char* base = (char*)d_ws;
  auto take = [&](size_t b) { char* p = base + off; off += (b + 255) & ~(size_t)255; return p; };
  u16*      x_bf   = (u16*)take((size_t)T_TOK * H_DIM * 2);
  u16*      W1_bf  = (u16*)take((size_t)M_DIM * H_DIM * 2);
  u16*      h1_bf  = (u16*)take((size_t)T_TOK * M_DIM * 2);
  u16*      Wd_bf  = (u16*)take((size_t)H_DIM * EFD * 2);      // big: [e][h][f]; fallback: Wdp
  u16*      actC   = (u16*)take((size_t)E_NUM * SLOTMAX * F_DIM * 2); // big: compact; fb: dense actS
  float*    comb   = (float*)take((size_t)T_TOK * E_NUM * 4);
  int*      list   = (int*)take((size_t)E_NUM * T_TOK * 4);
  float*    wlist  = (float*)take((size_t)E_NUM * T_TOK * 4);
  int*      counts = (int*)take(64 * 4);
  unsigned* emask  = (unsigned*)take((size_t)T_TOK * 4);
  int*      tokmap = (int*)take((size_t)T_TOK * 8 * 4);
  u16*      Wg_bf  = (u16*)take((size_t)E_NUM * F_DIM * H_DIM * 2);
  u16*      Wu_bf  = (u16*)take((size_t)E_NUM * F_DIM * H_DIM * 2);
  bool big = (off <= ws_size);
  // outE [16][2048][2048] bf16 = 128MB aliases Wg_bf+Wu_bf (134MB, dead after k8gu)
  u16* outE = Wg_bf;

  k_cvt<<<dim3((T_TOK * H_DIM / 8) / 256), 256, 0, stream>>>(x, x_bf, T_TOK * H_DIM / 8);
  k_cvt<<<dim3((M_DIM * H_DIM / 8) / 256), 256, 0, stream>>>(W1, W1_bf, M_DIM * H_DIM / 8);
  if (big) {
    k_cvt<<<dim3(16384), 256, 0, stream>>>(Wd, Wd_bf, E_NUM * H_DIM * F_DIM / 8);  // no transpose
    k_cvt<<<dim3(16384), 256, 0, stream>>>(Wg, Wg_bf, E_NUM * F_DIM * H_DIM / 8);
    k_cvt<<<dim3(16384), 256, 0, stream>>>(Wu, Wu_bf, E_NUM * F_DIM * H_DIM / 8);
  } else {
    k_cvt_wd<<<dim3(16384), 256, 0, stream>>>(Wd, Wd_bf);                          // transposed Wdp
    (void)hipMemsetAsync(actC, 0, (size_t)T_TOK * EFD * 2, stream);                // dense actS
  }

  k_gemm_h1<<<dim3(M_DIM / 64, T_TOK / 128), 256, 0, stream>>>(x_bf, W1_bf, M_DIM, H_DIM,
                                                               h1_bf, b1);
  k_router<<<dim3(T_TOK), 256, 0, stream>>>(x, gu, h1_bf, W2, b2, gw, Um, al, comb, emask);
  k_compact<<<dim3(E_NUM), 256, 0, stream>>>(comb, list, wlist, counts);

  if (big) {
    // fused gate+up -> compacted actC
    k8gu<<<dim3(F_DIM / 128, SLOTMAX / 256, E_NUM), 512, 131072, stream>>>(
        x_bf, Wg_bf, Wu_bf, list, wlist, counts, actC);
    // per-expert down -> outE (aliases Wg/Wu region, dead now)
    k8d<<<dim3(H_DIM / 256, SLOTMAX / 256, E_NUM), 512, 131072, stream>>>(
        actC, Wd_bf, counts, outE);
    // inverse map + deterministic gather-reduce
    k_tokmap<<<dim3(E_NUM), 256, 0, stream>>>(list, wlist, counts, emask, tokmap);
    k_gather<<<dim3(T_TOK), 256, 0, stream>>>(outE, tokmap, y);
  } else {
    k_gu_f32<<<dim3(F_DIM / 128, 16, E_NUM), 256, 0, stream>>>(x_bf, Wg, Wu,
                                                               list, wlist, counts, actC);
    k_down<<<dim3(256), 256, 0, stream>>>(actC, Wd_bf, y);
  }
}